// Round 1
// baseline (1180.448 us; speedup 1.0000x reference)
//
#include <hip/hip_runtime.h>
#include <math.h>

#define N_NODES 50000
#define N_EDGESI 800000
#define E_TOT   850000      // + self loops
#define HIDDEN  128
#define HEADS   8
#define HEAD_DIM 16
#define INPUT   300
#define BATCH   64

// ---- float <-> order-preserving uint (for atomic max on float) ----
__device__ __forceinline__ unsigned f2o(float f){
    unsigned u = __float_as_uint(f);
    return (u & 0x80000000u) ? ~u : (u | 0x80000000u);
}
__device__ __forceinline__ float o2f(unsigned u){
    return (u & 0x80000000u) ? __uint_as_float(u ^ 0x80000000u)
                             : __uint_as_float(~u);
}

__device__ __forceinline__ void edge_sd(int e, const int* __restrict__ ei, int& s, int& d){
    if (e < N_EDGESI){ s = ei[e]; d = ei[N_EDGESI + e]; }
    else { s = e - N_EDGESI; d = s; }
}

// ---- x = word_embed @ lin1_W + b   (50000 x 300 @ 300 x 128) ----
__global__ void lin1_kernel(const float* __restrict__ X, const float* __restrict__ W,
                            const float* __restrict__ b, float* __restrict__ out){
    __shared__ float rows[8][INPUT];
    int t  = threadIdx.x;
    int n0 = blockIdx.x * 8;
    for (int idx = t; idx < 8*INPUT; idx += 128){
        int r = idx / INPUT, c = idx - r*INPUT;
        rows[r][c] = X[(size_t)(n0 + r)*INPUT + c];
    }
    __syncthreads();
    float acc[8];
    float bias = b[t];
    #pragma unroll
    for (int r = 0; r < 8; r++) acc[r] = bias;
    for (int k = 0; k < INPUT; k++){
        float wv = W[k*HIDDEN + t];
        #pragma unroll
        for (int r = 0; r < 8; r++) acc[r] += rows[r][k]*wv;
    }
    #pragma unroll
    for (int r = 0; r < 8; r++) out[(size_t)(n0 + r)*HIDDEN + t] = acc[r];
}

// ---- h = x @ W  (+ fused per-head alpha_src/alpha_dst reductions) ----
__global__ void gat_gemm_kernel(const float* __restrict__ X, const float* __restrict__ W,
                                const float* __restrict__ asrc, const float* __restrict__ adst,
                                float* __restrict__ H, float* __restrict__ alpha_src,
                                float* __restrict__ alpha_dst){
    __shared__ float rows[8][HIDDEN];
    int t  = threadIdx.x;
    int n0 = blockIdx.x * 8;
    for (int idx = t; idx < 8*HIDDEN; idx += 128){
        int r = idx >> 7, c = idx & 127;
        rows[r][c] = X[(size_t)(n0 + r)*HIDDEN + c];
    }
    __syncthreads();
    float acc[8];
    #pragma unroll
    for (int r = 0; r < 8; r++) acc[r] = 0.f;
    for (int k = 0; k < HIDDEN; k++){
        float wv = W[k*HIDDEN + t];
        #pragma unroll
        for (int r = 0; r < 8; r++) acc[r] += rows[r][k]*wv;
    }
    float as = asrc[t], ad = adst[t];
    int head   = t >> 4;
    int lane16 = t & 15;
    #pragma unroll
    for (int r = 0; r < 8; r++){
        H[(size_t)(n0 + r)*HIDDEN + t] = acc[r];
        float ps = acc[r]*as, pd = acc[r]*ad;
        #pragma unroll
        for (int m = 8; m >= 1; m >>= 1){
            ps += __shfl_xor(ps, m);
            pd += __shfl_xor(pd, m);
        }
        if (lane16 == 0){
            alpha_src[(n0 + r)*HEADS + head] = ps;
            alpha_dst[(n0 + r)*HEADS + head] = pd;
        }
    }
}

// ---- edge pass 1: segment max of leaky_relu(asrc[s]+adst[d]) over dst ----
__global__ void edge_max_kernel(const int* __restrict__ ei, const float* __restrict__ a_s,
                                const float* __restrict__ a_d, unsigned* __restrict__ emax){
    int tid = blockIdx.x*blockDim.x + threadIdx.x;
    if (tid >= E_TOT*HEADS) return;
    int e = tid >> 3, hh = tid & 7;
    int s, d; edge_sd(e, ei, s, d);
    float v = a_s[s*HEADS + hh] + a_d[d*HEADS + hh];
    v = v > 0.f ? v : 0.2f*v;
    atomicMax(&emax[d*HEADS + hh], f2o(v));
}

// ---- edge pass 2: ee = exp(e - emax[d]); denom[d] += ee ----
__global__ void edge_exp_kernel(const int* __restrict__ ei, const float* __restrict__ a_s,
                                const float* __restrict__ a_d, const unsigned* __restrict__ emax,
                                float* __restrict__ ee, float* __restrict__ denom){
    int tid = blockIdx.x*blockDim.x + threadIdx.x;
    if (tid >= E_TOT*HEADS) return;
    int e = tid >> 3, hh = tid & 7;
    int s, d; edge_sd(e, ei, s, d);
    float v = a_s[s*HEADS + hh] + a_d[d*HEADS + hh];
    v = v > 0.f ? v : 0.2f*v;
    float ex = expf(v - o2f(emax[d*HEADS + hh]));
    ee[tid] = ex;
    atomicAdd(&denom[d*HEADS + hh], ex);
}

// ---- edge pass 3: alpha = ee / denom[d]   (in place) ----
__global__ void alpha_div_kernel(const int* __restrict__ ei, const float* __restrict__ denom,
                                 float* __restrict__ ee){
    int tid = blockIdx.x*blockDim.x + threadIdx.x;
    if (tid >= E_TOT*HEADS) return;
    int e = tid >> 3, hh = tid & 7;
    int s, d; edge_sd(e, ei, s, d);
    ee[tid] = ee[tid] / denom[d*HEADS + hh];
}

// ---- edge pass 4: agg[d,:] += h[s,:] * alpha[e,head]  ----
__global__ void aggregate_kernel(const int* __restrict__ ei, const float* __restrict__ H,
                                 const float* __restrict__ alpha, float* __restrict__ agg){
    int tid = blockIdx.x*blockDim.x + threadIdx.x;
    if (tid >= (int)((long long)E_TOT*HIDDEN)) return;
    int e = tid >> 7, c = tid & 127;
    int s, d; edge_sd(e, ei, s, d);
    float a = alpha[e*HEADS + (c >> 4)];
    atomicAdd(&agg[(size_t)d*HIDDEN + c], H[(size_t)s*HIDDEN + c] * a);
}

// ---- x = elu(agg + bias) ----
__global__ void finish_kernel(const float* __restrict__ agg, const float* __restrict__ bias,
                              float* __restrict__ x){
    int tid = blockIdx.x*blockDim.x + threadIdx.x;
    if (tid >= N_NODES*HIDDEN) return;
    int c = tid & 127;
    float v = agg[tid] + bias[c];
    x[tid] = v > 0.f ? v : expm1f(v);
}

// ---- total_score[b] = dot(x[target[b]], lin3_W) + lin3_b ----
__global__ void score_kernel(const float* __restrict__ x, const int* __restrict__ tgt,
                             const float* __restrict__ w, const float* __restrict__ b,
                             float* __restrict__ scores, float* __restrict__ dout){
    int bb = blockIdx.x, t = threadIdx.x;   // 64 threads
    const float* row = x + (size_t)tgt[bb]*HIDDEN;
    float v = row[t]*w[t] + row[t + 64]*w[t + 64];
    #pragma unroll
    for (int m = 32; m >= 1; m >>= 1) v += __shfl_xor(v, m);
    if (t == 0){
        float sc = v + b[0];
        scores[bb] = sc;
        dout[bb]   = sc;
    }
}

// ---- loss = mean(relu(1 - (pos - neg))) ----
__global__ void loss_kernel(const float* __restrict__ scores, float* __restrict__ dout){
    int t = threadIdx.x;    // 64 threads, first 32 carry values
    float v = 0.f;
    if (t < 32){
        float dlt = 1.0f - (scores[t] - scores[t + 32]);
        v = dlt > 0.f ? dlt : 0.f;
    }
    #pragma unroll
    for (int m = 32; m >= 1; m >>= 1) v += __shfl_xor(v, m);
    if (t == 0) dout[BATCH] = v * (1.0f/32.0f);
}

extern "C" void kernel_launch(void* const* d_in, const int* in_sizes, int n_in,
                              void* d_out, int out_size, void* d_ws, size_t ws_size,
                              hipStream_t stream) {
    const float* word   = (const float*)d_in[0];
    const int*   ei     = (const int*)  d_in[1];
    const int*   tgt    = (const int*)  d_in[2];
    // d_in[3] = label_id (unused by reference outputs)
    const float* lin1W  = (const float*)d_in[4];
    const float* lin1b  = (const float*)d_in[5];
    const float* gatW   = (const float*)d_in[6];
    const float* attS   = (const float*)d_in[7];
    const float* attD   = (const float*)d_in[8];
    const float* gatB   = (const float*)d_in[9];
    const float* lin3W  = (const float*)d_in[10];
    const float* lin3b  = (const float*)d_in[11];

    char* ws = (char*)d_ws;
    size_t off = 0;
    float*    x      = (float*)(ws + off); off += (size_t)N_NODES*HIDDEN*4;
    float*    h      = (float*)(ws + off); off += (size_t)N_NODES*HIDDEN*4;
    float*    agg    = (float*)(ws + off); off += (size_t)N_NODES*HIDDEN*4;
    float*    ee     = (float*)(ws + off); off += (size_t)E_TOT*HEADS*4;
    float*    a_s    = (float*)(ws + off); off += (size_t)N_NODES*HEADS*4;
    float*    a_d    = (float*)(ws + off); off += (size_t)N_NODES*HEADS*4;
    unsigned* emax   = (unsigned*)(ws + off); off += (size_t)N_NODES*HEADS*4;
    float*    denom  = (float*)(ws + off); off += (size_t)N_NODES*HEADS*4;
    float*    scores = (float*)(ws + off); off += 256;

    lin1_kernel<<<N_NODES/8, 128, 0, stream>>>(word, lin1W, lin1b, x);

    const int eb = (E_TOT*HEADS + 255)/256;
    const int ab = (int)(((long long)E_TOT*HIDDEN + 255)/256);

    for (int L = 0; L < 2; L++){
        hipMemsetAsync(emax,  0, (size_t)N_NODES*HEADS*4, stream);
        hipMemsetAsync(denom, 0, (size_t)N_NODES*HEADS*4, stream);
        hipMemsetAsync(agg,   0, (size_t)N_NODES*HIDDEN*4, stream);

        gat_gemm_kernel<<<N_NODES/8, 128, 0, stream>>>(
            x, gatW + (size_t)L*HIDDEN*HIDDEN, attS + L*HEADS*HEAD_DIM,
            attD + L*HEADS*HEAD_DIM, h, a_s, a_d);

        edge_max_kernel <<<eb, 256, 0, stream>>>(ei, a_s, a_d, emax);
        edge_exp_kernel <<<eb, 256, 0, stream>>>(ei, a_s, a_d, emax, ee, denom);
        alpha_div_kernel<<<eb, 256, 0, stream>>>(ei, denom, ee);
        aggregate_kernel<<<ab, 256, 0, stream>>>(ei, h, ee, agg);
        finish_kernel<<<(N_NODES*HIDDEN + 255)/256, 256, 0, stream>>>(
            agg, gatB + L*HIDDEN, x);
    }

    score_kernel<<<BATCH, 64, 0, stream>>>(x, tgt, lin3W, lin3b, scores, (float*)d_out);
    loss_kernel <<<1, 64, 0, stream>>>(scores, (float*)d_out);
}

// Round 2
// 554.516 us; speedup vs baseline: 2.1288x; 2.1288x over previous
//
#include <hip/hip_runtime.h>
#include <math.h>

#define N_NODES 50000
#define N_EDGESI 800000
#define E_TOT   850000      // + self loops
#define HIDDEN  128
#define HEADS   8
#define HEAD_DIM 16
#define INPUT   300
#define BATCH   64

__device__ __forceinline__ void edge_sd(int e, const int* __restrict__ ei, int& s, int& d){
    if (e < N_EDGESI){ s = ei[e]; d = ei[N_EDGESI + e]; }
    else { s = e - N_EDGESI; d = s; }
}

// ---- x = word_embed @ lin1_W + b   (50000 x 300 @ 300 x 128) ----
__global__ void lin1_kernel(const float* __restrict__ X, const float* __restrict__ W,
                            const float* __restrict__ b, float* __restrict__ out){
    __shared__ float rows[8][INPUT];
    int t  = threadIdx.x;
    int n0 = blockIdx.x * 8;
    for (int idx = t; idx < 8*INPUT; idx += 128){
        int r = idx / INPUT, c = idx - r*INPUT;
        rows[r][c] = X[(size_t)(n0 + r)*INPUT + c];
    }
    __syncthreads();
    float acc[8];
    float bias = b[t];
    #pragma unroll
    for (int r = 0; r < 8; r++) acc[r] = bias;
    for (int k = 0; k < INPUT; k++){
        float wv = W[k*HIDDEN + t];
        #pragma unroll
        for (int r = 0; r < 8; r++) acc[r] += rows[r][k]*wv;
    }
    #pragma unroll
    for (int r = 0; r < 8; r++) out[(size_t)(n0 + r)*HIDDEN + t] = acc[r];
}

// ---- h = x @ W  (+ fused per-head alpha_src/alpha_dst reductions) ----
__global__ void gat_gemm_kernel(const float* __restrict__ X, const float* __restrict__ W,
                                const float* __restrict__ asrc, const float* __restrict__ adst,
                                float* __restrict__ H, float* __restrict__ alpha_src,
                                float* __restrict__ alpha_dst){
    __shared__ float rows[8][HIDDEN];
    int t  = threadIdx.x;
    int n0 = blockIdx.x * 8;
    for (int idx = t; idx < 8*HIDDEN; idx += 128){
        int r = idx >> 7, c = idx & 127;
        rows[r][c] = X[(size_t)(n0 + r)*HIDDEN + c];
    }
    __syncthreads();
    float acc[8];
    #pragma unroll
    for (int r = 0; r < 8; r++) acc[r] = 0.f;
    for (int k = 0; k < HIDDEN; k++){
        float wv = W[k*HIDDEN + t];
        #pragma unroll
        for (int r = 0; r < 8; r++) acc[r] += rows[r][k]*wv;
    }
    float as = asrc[t], ad = adst[t];
    int head   = t >> 4;
    int lane16 = t & 15;
    #pragma unroll
    for (int r = 0; r < 8; r++){
        H[(size_t)(n0 + r)*HIDDEN + t] = acc[r];
        float ps = acc[r]*as, pd = acc[r]*ad;
        #pragma unroll
        for (int m = 8; m >= 1; m >>= 1){
            ps += __shfl_xor(ps, m);
            pd += __shfl_xor(pd, m);
        }
        if (lane16 == 0){
            alpha_src[(n0 + r)*HEADS + head] = ps;
            alpha_dst[(n0 + r)*HEADS + head] = pd;
        }
    }
}

// ======================= CSR build (once) =======================
__global__ void deg_kernel(const int* __restrict__ ei, int* __restrict__ deg){
    int e = blockIdx.x*256 + threadIdx.x;
    if (e >= E_TOT) return;
    int s, d; edge_sd(e, ei, s, d);
    atomicAdd(&deg[d], 1);
}

// exclusive scan, 1024-element blocks
__global__ void scan_block_kernel(const int* __restrict__ deg, int* __restrict__ scanout,
                                  int* __restrict__ blocksums){
    __shared__ int buf[1024];
    int gid = blockIdx.x*1024 + threadIdx.x;
    int v = (gid < N_NODES) ? deg[gid] : 0;
    buf[threadIdx.x] = v;
    __syncthreads();
    for (int off = 1; off < 1024; off <<= 1){
        int t = (threadIdx.x >= off) ? buf[threadIdx.x - off] : 0;
        __syncthreads();
        buf[threadIdx.x] += t;
        __syncthreads();
    }
    if (gid < N_NODES) scanout[gid] = buf[threadIdx.x] - v;   // exclusive
    if (threadIdx.x == 1023) blocksums[blockIdx.x] = buf[1023];
}

__global__ void scan_sums_kernel(int* __restrict__ blocksums, int nb){
    if (threadIdx.x == 0){
        int acc = 0;
        for (int i = 0; i < nb; i++){ int v = blocksums[i]; blocksums[i] = acc; acc += v; }
    }
}

__global__ void scan_add_kernel(const int* __restrict__ scanout, const int* __restrict__ blocksums,
                                int* __restrict__ row_ptr, int* __restrict__ cursor){
    int i = blockIdx.x*256 + threadIdx.x;
    if (i < N_NODES){
        int v = scanout[i] + blocksums[i >> 10];
        row_ptr[i] = v;
        cursor[i]  = v;
    }
    if (i == 0) row_ptr[N_NODES] = E_TOT;
}

__global__ void scatter_kernel(const int* __restrict__ ei, int* __restrict__ cursor,
                               int* __restrict__ col_src){
    int e = blockIdx.x*256 + threadIdx.x;
    if (e >= E_TOT) return;
    int s, d; edge_sd(e, ei, s, d);
    int pos = atomicAdd(&cursor[d], 1);
    col_src[pos] = s;
}

// ===== fused per-dst softmax + aggregate + bias + ELU: one wave per node =====
__global__ void gat_aggregate_kernel(const int* __restrict__ row_ptr, const int* __restrict__ col_src,
                                     const float* __restrict__ H, const float* __restrict__ a_s,
                                     const float* __restrict__ a_d, const float* __restrict__ bias,
                                     float* __restrict__ xout){
    int wave = threadIdx.x >> 6;            // 4 waves / block
    int lane = threadIdx.x & 63;
    int d = blockIdx.x*4 + wave;
    if (d >= N_NODES) return;
    int start = row_ptr[d], end = row_ptr[d + 1];
    int deg = end - start;

    float ad[8];
    #pragma unroll
    for (int h = 0; h < 8; h++) ad[h] = a_d[d*8 + h];

    // ---- phase A: per-head max of leaky_relu(a_s[s]+a_d[d]) ----
    float lg[8];                            // cached logits (valid when deg<=64)
    int   have = 0;
    float m[8];
    #pragma unroll
    for (int h = 0; h < 8; h++) m[h] = -1e30f;
    for (int p = start + lane; p < end; p += 64){
        int s = col_src[p];
        #pragma unroll
        for (int h = 0; h < 8; h++){
            float v = a_s[s*8 + h] + ad[h];
            v = v > 0.f ? v : 0.2f*v;
            lg[h] = v;
            m[h]  = fmaxf(m[h], v);
        }
        have++;
    }
    #pragma unroll
    for (int h = 0; h < 8; h++){
        float v = m[h];
        #pragma unroll
        for (int off = 32; off >= 1; off >>= 1) v = fmaxf(v, __shfl_xor(v, off));
        m[h] = v;
    }

    // ---- phase B: per-head sum of exp(l - m) ----
    float ssum[8];
    #pragma unroll
    for (int h = 0; h < 8; h++) ssum[h] = 0.f;
    if (deg <= 64){
        if (have){
            #pragma unroll
            for (int h = 0; h < 8; h++) ssum[h] = __expf(lg[h] - m[h]);
        }
    } else {
        for (int p = start + lane; p < end; p += 64){
            int s = col_src[p];
            #pragma unroll
            for (int h = 0; h < 8; h++){
                float v = a_s[s*8 + h] + ad[h];
                v = v > 0.f ? v : 0.2f*v;
                ssum[h] += __expf(v - m[h]);
            }
        }
    }
    #pragma unroll
    for (int h = 0; h < 8; h++){
        float v = ssum[h];
        #pragma unroll
        for (int off = 32; off >= 1; off >>= 1) v += __shfl_xor(v, off);
        ssum[h] = 1.0f / v;                 // inverse denom
    }

    // ---- phase C: acc[c] = sum_e alpha * h[s][c], 2 channels/lane ----
    int   hme = lane >> 3;                  // head of channels 2*lane, 2*lane+1
    float adh = ad[hme], mh = m[hme], dh = ssum[hme];
    float acc0 = 0.f, acc1 = 0.f;
    for (int p = start; p < end; p++){
        int s = col_src[p];
        float v = a_s[s*8 + hme] + adh;
        v = v > 0.f ? v : 0.2f*v;
        float a = __expf(v - mh) * dh;
        float2 hv = *(const float2*)&H[(size_t)s*HIDDEN + 2*lane];
        acc0 += hv.x * a;
        acc1 += hv.y * a;
    }
    float o0 = acc0 + bias[2*lane];
    float o1 = acc1 + bias[2*lane + 1];
    o0 = o0 > 0.f ? o0 : expm1f(o0);
    o1 = o1 > 0.f ? o1 : expm1f(o1);
    float2 o = {o0, o1};
    *(float2*)&xout[(size_t)d*HIDDEN + 2*lane] = o;
}

// ---- total_score[b] = dot(x[target[b]], lin3_W) + lin3_b ----
__global__ void score_kernel(const float* __restrict__ x, const int* __restrict__ tgt,
                             const float* __restrict__ w, const float* __restrict__ b,
                             float* __restrict__ scores, float* __restrict__ dout){
    int bb = blockIdx.x, t = threadIdx.x;   // 64 threads
    const float* row = x + (size_t)tgt[bb]*HIDDEN;
    float v = row[t]*w[t] + row[t + 64]*w[t + 64];
    #pragma unroll
    for (int m = 32; m >= 1; m >>= 1) v += __shfl_xor(v, m);
    if (t == 0){
        float sc = v + b[0];
        scores[bb] = sc;
        dout[bb]   = sc;
    }
}

// ---- loss = mean(relu(1 - (pos - neg))) ----
__global__ void loss_kernel(const float* __restrict__ scores, float* __restrict__ dout){
    int t = threadIdx.x;
    float v = 0.f;
    if (t < 32){
        float dlt = 1.0f - (scores[t] - scores[t + 32]);
        v = dlt > 0.f ? dlt : 0.f;
    }
    #pragma unroll
    for (int m = 32; m >= 1; m >>= 1) v += __shfl_xor(v, m);
    if (t == 0) dout[BATCH] = v * (1.0f/32.0f);
}

extern "C" void kernel_launch(void* const* d_in, const int* in_sizes, int n_in,
                              void* d_out, int out_size, void* d_ws, size_t ws_size,
                              hipStream_t stream) {
    const float* word   = (const float*)d_in[0];
    const int*   ei     = (const int*)  d_in[1];
    const int*   tgt    = (const int*)  d_in[2];
    const float* lin1W  = (const float*)d_in[4];
    const float* lin1b  = (const float*)d_in[5];
    const float* gatW   = (const float*)d_in[6];
    const float* attS   = (const float*)d_in[7];
    const float* attD   = (const float*)d_in[8];
    const float* gatB   = (const float*)d_in[9];
    const float* lin3W  = (const float*)d_in[10];
    const float* lin3b  = (const float*)d_in[11];

    char* ws = (char*)d_ws;
    size_t off = 0;
    float* x       = (float*)(ws + off); off += (size_t)N_NODES*HIDDEN*4;
    float* h       = (float*)(ws + off); off += (size_t)N_NODES*HIDDEN*4;
    float* a_s     = (float*)(ws + off); off += (size_t)N_NODES*HEADS*4;
    float* a_d     = (float*)(ws + off); off += (size_t)N_NODES*HEADS*4;
    int*   deg     = (int*)(ws + off);   off += (size_t)(N_NODES + 16)*4;
    int*   scantmp = (int*)(ws + off);   off += (size_t)(N_NODES + 16)*4;
    int*   bsums   = (int*)(ws + off);   off += 1024;
    int*   row_ptr = (int*)(ws + off);   off += (size_t)(N_NODES + 16)*4;
    int*   cursor  = (int*)(ws + off);   off += (size_t)(N_NODES + 16)*4;
    int*   col_src = (int*)(ws + off);   off += (size_t)E_TOT*4;
    float* scores  = (float*)(ws + off); off += 256;

    const int EB  = (E_TOT + 255)/256;
    const int NB  = (N_NODES + 255)/256;
    const int SB  = (N_NODES + 1023)/1024;   // 49 scan blocks

    // ---- CSR build (once) ----
    hipMemsetAsync(deg, 0, (size_t)N_NODES*4, stream);
    deg_kernel       <<<EB, 256, 0, stream>>>(ei, deg);
    scan_block_kernel<<<SB, 1024, 0, stream>>>(deg, scantmp, bsums);
    scan_sums_kernel <<<1, 64, 0, stream>>>(bsums, SB);
    scan_add_kernel  <<<NB, 256, 0, stream>>>(scantmp, bsums, row_ptr, cursor);
    scatter_kernel   <<<EB, 256, 0, stream>>>(ei, cursor, col_src);

    // ---- network ----
    lin1_kernel<<<N_NODES/8, 128, 0, stream>>>(word, lin1W, lin1b, x);

    for (int L = 0; L < 2; L++){
        gat_gemm_kernel<<<N_NODES/8, 128, 0, stream>>>(
            x, gatW + (size_t)L*HIDDEN*HIDDEN, attS + L*HEADS*HEAD_DIM,
            attD + L*HEADS*HEAD_DIM, h, a_s, a_d);
        gat_aggregate_kernel<<<(N_NODES + 3)/4, 256, 0, stream>>>(
            row_ptr, col_src, h, a_s, a_d, gatB + L*HIDDEN, x);
    }

    score_kernel<<<BATCH, 64, 0, stream>>>(x, tgt, lin3W, lin3b, scores, (float*)d_out);
    loss_kernel <<<1, 64, 0, stream>>>(scores, (float*)d_out);
}

// Round 3
// 549.869 us; speedup vs baseline: 2.1468x; 1.0085x over previous
//
#include <hip/hip_runtime.h>
#include <math.h>

#define N_NODES 50000
#define N_EDGESI 800000
#define E_TOT   850000      // + self loops
#define HIDDEN  128
#define HEADS   8
#define HEAD_DIM 16
#define INPUT   300
#define BATCH   64

typedef __bf16 bf16_t;
typedef bf16_t bf16x8 __attribute__((ext_vector_type(8)));
typedef bf16_t bf16x4 __attribute__((ext_vector_type(4)));
typedef float  f32x4  __attribute__((ext_vector_type(4)));

__device__ __forceinline__ void edge_sd(int e, const int* __restrict__ ei, int& s, int& d){
    if (e < N_EDGESI){ s = ei[e]; d = ei[N_EDGESI + e]; }
    else { s = e - N_EDGESI; d = s; }
}

// =================== MFMA GEMM (fp32 via bf16 hi/lo split) ===================
// C[M x 128] = A[M x K_REAL] * B[K_REAL x 128]   (+ optional bias, + optional
// fused alpha tile using Wa[K_REAL x 16]).  Block: 256 thr, 64 rows, K chunks of 64.
template<int K_REAL, int K_PAD, int NT, bool BIAS_EPI, bool ALPHA>
__global__ __launch_bounds__(256, 2)
void mfma_gemm_kernel(const float* __restrict__ A, const float* __restrict__ B,
                      const float* __restrict__ Wa, const float* __restrict__ bias,
                      float* __restrict__ out, float* __restrict__ asrc_out,
                      float* __restrict__ adst_out, int M)
{
    static_assert(K_REAL % 4 == 0 && K_PAD % 64 == 0, "");
    constexpr int NCOL = NT * 16;
    constexpr int NCH  = K_PAD / 64;
    __shared__ __align__(16) bf16_t aHi[64][72];
    __shared__ __align__(16) bf16_t aLo[64][72];
    __shared__ __align__(16) bf16_t bHi[8][NCOL][8];
    __shared__ __align__(16) bf16_t bLo[8][NCOL][8];

    int tid  = threadIdx.x;
    int lane = tid & 63;
    int w    = tid >> 6;
    int l15  = lane & 15, lg = lane >> 4;
    int wrh  = w >> 1;            // row half (0/1): rows wrh*32 .. +31
    int wch  = w & 1;             // col half (0/1): col tiles wch*4 .. +3
    int n0   = blockIdx.x * 64;

    f32x4 acc[2][4] = {};
    f32x4 accA[2]   = {};

    for (int ch = 0; ch < NCH; ch++){
        int kb = ch * 64;
        if (ch) __syncthreads();

        // ---- stage A chunk: 64 rows x 64 k ----
        #pragma unroll
        for (int it = 0; it < 4; it++){
            int idx = tid + it*256;           // 0..1023
            int r = idx >> 4, f4 = idx & 15;
            int k = kb + f4*4;
            int gr = n0 + r;
            float4 v = {0.f, 0.f, 0.f, 0.f};
            if (gr < M && k < K_REAL) v = *(const float4*)&A[(size_t)gr*K_REAL + k];
            float f[4] = {v.x, v.y, v.z, v.w};
            bf16x4 hv, lv;
            #pragma unroll
            for (int q = 0; q < 4; q++){
                bf16_t hi = (bf16_t)f[q];
                hv[q] = hi;
                lv[q] = (bf16_t)(f[q] - (float)hi);
            }
            *(bf16x4*)&aHi[r][f4*4] = hv;
            *(bf16x4*)&aLo[r][f4*4] = lv;
        }

        // ---- stage B chunk: 64 k x NCOL, frag-packed [k/8][col^swz][k%8] ----
        constexpr int BIT = (64*NCOL)/256;
        #pragma unroll
        for (int it = 0; it < BIT; it++){
            int idx = tid + it*256;
            int col = idx % NCOL;
            int k   = idx / NCOL;
            int gk  = kb + k;
            float v = 0.f;
            if (gk < K_REAL){
                if (!ALPHA || col < 128) v = B[gk*128 + col];
                else                     v = Wa[gk*16 + (col - 128)];
            }
            bf16_t hi = (bf16_t)v;
            bf16_t lo = (bf16_t)(v - (float)hi);
            int colp = col ^ (2*((k>>3)&3));
            bHi[k>>3][colp][k&7] = hi;
            bLo[k>>3][colp][k&7] = lo;
        }
        __syncthreads();

        // ---- MFMA: 2 k-steps of 32 ----
        #pragma unroll
        for (int ks = 0; ks < 2; ks++){
            bf16x8 ah[2], al[2];
            #pragma unroll
            for (int rt = 0; rt < 2; rt++){
                int row = wrh*32 + rt*16 + l15;
                ah[rt] = *(const bf16x8*)&aHi[row][ks*32 + lg*8];
                al[rt] = *(const bf16x8*)&aLo[row][ks*32 + lg*8];
            }
            int g   = ks*4 + lg;
            int swz = 2*(g & 3);
            #pragma unroll
            for (int c = 0; c < 4; c++){
                int ct   = wch*4 + c;
                int colp = (ct*16 + l15) ^ swz;
                bf16x8 bh = *(const bf16x8*)&bHi[g][colp][0];
                bf16x8 bl = *(const bf16x8*)&bLo[g][colp][0];
                #pragma unroll
                for (int rt = 0; rt < 2; rt++){
                    acc[rt][c] = __builtin_amdgcn_mfma_f32_16x16x32_bf16(ah[rt], bh, acc[rt][c], 0,0,0);
                    acc[rt][c] = __builtin_amdgcn_mfma_f32_16x16x32_bf16(ah[rt], bl, acc[rt][c], 0,0,0);
                    acc[rt][c] = __builtin_amdgcn_mfma_f32_16x16x32_bf16(al[rt], bh, acc[rt][c], 0,0,0);
                }
            }
            if (ALPHA && wch == 1){
                int colp = (128 + l15) ^ swz;
                bf16x8 bh = *(const bf16x8*)&bHi[g][colp][0];
                bf16x8 bl = *(const bf16x8*)&bLo[g][colp][0];
                #pragma unroll
                for (int rt = 0; rt < 2; rt++){
                    accA[rt] = __builtin_amdgcn_mfma_f32_16x16x32_bf16(ah[rt], bh, accA[rt], 0,0,0);
                    accA[rt] = __builtin_amdgcn_mfma_f32_16x16x32_bf16(ah[rt], bl, accA[rt], 0,0,0);
                    accA[rt] = __builtin_amdgcn_mfma_f32_16x16x32_bf16(al[rt], bh, accA[rt], 0,0,0);
                }
            }
        }
    }

    // ---- epilogue: D row = (lane>>4)*4 + reg, col = lane&15 ----
    int mbase = n0 + wrh*32 + lg*4;
    #pragma unroll
    for (int rt = 0; rt < 2; rt++){
        #pragma unroll
        for (int c = 0; c < 4; c++){
            int ct  = wch*4 + c;
            int col = ct*16 + l15;
            float bv = BIAS_EPI ? bias[col] : 0.f;
            #pragma unroll
            for (int r = 0; r < 4; r++){
                int m = mbase + rt*16 + r;
                if (m < M) out[(size_t)m*128 + col] = acc[rt][c][r] + bv;
            }
        }
        if (ALPHA && wch == 1){
            #pragma unroll
            for (int r = 0; r < 4; r++){
                int m = mbase + rt*16 + r;
                if (m < M){
                    float v = accA[rt][r];
                    if (l15 < 8) asrc_out[m*8 + l15]       = v;
                    else         adst_out[m*8 + (l15 - 8)] = v;
                }
            }
        }
    }
}

// ---- Wa[k][j] = sum_d W[k][j*16+d]*a_src[j][d]  (j<8: src, j>=8: dst) ----
__global__ void wa_kernel(const float* __restrict__ W, const float* __restrict__ as,
                          const float* __restrict__ ad, float* __restrict__ Wa){
    int k = threadIdx.x;   // 128
    #pragma unroll
    for (int j = 0; j < 8; j++){
        float s1 = 0.f, s2 = 0.f;
        #pragma unroll
        for (int d = 0; d < 16; d++){
            float wv = W[k*128 + j*16 + d];
            s1 += wv * as[j*16 + d];
            s2 += wv * ad[j*16 + d];
        }
        Wa[k*16 + j]     = s1;
        Wa[k*16 + 8 + j] = s2;
    }
}

// ======================= CSR build (once) =======================
__global__ void deg_kernel(const int* __restrict__ ei, int* __restrict__ deg){
    int e = blockIdx.x*256 + threadIdx.x;
    if (e >= E_TOT) return;
    int s, d; edge_sd(e, ei, s, d);
    atomicAdd(&deg[d], 1);
}

__global__ void scan_block_kernel(const int* __restrict__ deg, int* __restrict__ scanout,
                                  int* __restrict__ blocksums){
    __shared__ int buf[1024];
    int gid = blockIdx.x*1024 + threadIdx.x;
    int v = (gid < N_NODES) ? deg[gid] : 0;
    buf[threadIdx.x] = v;
    __syncthreads();
    for (int off = 1; off < 1024; off <<= 1){
        int t = (threadIdx.x >= off) ? buf[threadIdx.x - off] : 0;
        __syncthreads();
        buf[threadIdx.x] += t;
        __syncthreads();
    }
    if (gid < N_NODES) scanout[gid] = buf[threadIdx.x] - v;   // exclusive
    if (threadIdx.x == 1023) blocksums[blockIdx.x] = buf[1023];
}

__global__ void scan_sums_kernel(int* __restrict__ blocksums, int nb){
    if (threadIdx.x == 0){
        int acc = 0;
        for (int i = 0; i < nb; i++){ int v = blocksums[i]; blocksums[i] = acc; acc += v; }
    }
}

__global__ void scan_add_kernel(const int* __restrict__ scanout, const int* __restrict__ blocksums,
                                int* __restrict__ row_ptr, int* __restrict__ cursor){
    int i = blockIdx.x*256 + threadIdx.x;
    if (i < N_NODES){
        int v = scanout[i] + blocksums[i >> 10];
        row_ptr[i] = v;
        cursor[i]  = v;
    }
    if (i == 0) row_ptr[N_NODES] = E_TOT;
}

__global__ void scatter_kernel(const int* __restrict__ ei, int* __restrict__ cursor,
                               int* __restrict__ col_src){
    int e = blockIdx.x*256 + threadIdx.x;
    if (e >= E_TOT) return;
    int s, d; edge_sd(e, ei, s, d);
    int pos = atomicAdd(&cursor[d], 1);
    col_src[pos] = s;
}

// ===== fused per-dst softmax + aggregate + bias + ELU: one wave per node =====
__global__ void gat_aggregate_kernel(const int* __restrict__ row_ptr, const int* __restrict__ col_src,
                                     const float* __restrict__ H, const float* __restrict__ a_s,
                                     const float* __restrict__ a_d, const float* __restrict__ bias,
                                     float* __restrict__ xout){
    int wave = threadIdx.x >> 6;            // 4 waves / block
    int lane = threadIdx.x & 63;
    int d = blockIdx.x*4 + wave;
    if (d >= N_NODES) return;
    int start = row_ptr[d], end = row_ptr[d + 1];
    int deg = end - start;

    float ad[8];
    #pragma unroll
    for (int h = 0; h < 8; h++) ad[h] = a_d[d*8 + h];

    // ---- phase A: per-head max of leaky_relu(a_s[s]+a_d[d]) ----
    float lg[8];
    int   have = 0;
    float m[8];
    #pragma unroll
    for (int h = 0; h < 8; h++) m[h] = -1e30f;
    for (int p = start + lane; p < end; p += 64){
        int s = col_src[p];
        #pragma unroll
        for (int h = 0; h < 8; h++){
            float v = a_s[s*8 + h] + ad[h];
            v = v > 0.f ? v : 0.2f*v;
            lg[h] = v;
            m[h]  = fmaxf(m[h], v);
        }
        have++;
    }
    #pragma unroll
    for (int h = 0; h < 8; h++){
        float v = m[h];
        #pragma unroll
        for (int off = 32; off >= 1; off >>= 1) v = fmaxf(v, __shfl_xor(v, off));
        m[h] = v;
    }

    // ---- phase B: per-head sum of exp(l - m) ----
    float ssum[8];
    #pragma unroll
    for (int h = 0; h < 8; h++) ssum[h] = 0.f;
    if (deg <= 64){
        if (have){
            #pragma unroll
            for (int h = 0; h < 8; h++) ssum[h] = __expf(lg[h] - m[h]);
        }
    } else {
        for (int p = start + lane; p < end; p += 64){
            int s = col_src[p];
            #pragma unroll
            for (int h = 0; h < 8; h++){
                float v = a_s[s*8 + h] + ad[h];
                v = v > 0.f ? v : 0.2f*v;
                ssum[h] += __expf(v - m[h]);
            }
        }
    }
    #pragma unroll
    for (int h = 0; h < 8; h++){
        float v = ssum[h];
        #pragma unroll
        for (int off = 32; off >= 1; off >>= 1) v += __shfl_xor(v, off);
        ssum[h] = 1.0f / v;
    }

    // ---- phase C: acc[c] = sum_e alpha * h[s][c], 2 channels/lane, 2-wide ILP ----
    int   hme = lane >> 3;
    float adh = ad[hme], mh = m[hme], dh = ssum[hme];
    float acc0 = 0.f, acc1 = 0.f;
    int p = start;
    for (; p + 1 < end; p += 2){
        int s0 = col_src[p], s1 = col_src[p+1];
        float2 h0 = *(const float2*)&H[(size_t)s0*HIDDEN + 2*lane];
        float2 h1 = *(const float2*)&H[(size_t)s1*HIDDEN + 2*lane];
        float v0 = a_s[s0*8 + hme] + adh; v0 = v0 > 0.f ? v0 : 0.2f*v0;
        float v1 = a_s[s1*8 + hme] + adh; v1 = v1 > 0.f ? v1 : 0.2f*v1;
        float a0 = __expf(v0 - mh)*dh;
        float a1 = __expf(v1 - mh)*dh;
        acc0 += h0.x*a0 + h1.x*a1;
        acc1 += h0.y*a0 + h1.y*a1;
    }
    if (p < end){
        int s0 = col_src[p];
        float2 h0 = *(const float2*)&H[(size_t)s0*HIDDEN + 2*lane];
        float v0 = a_s[s0*8 + hme] + adh; v0 = v0 > 0.f ? v0 : 0.2f*v0;
        float a0 = __expf(v0 - mh)*dh;
        acc0 += h0.x*a0;
        acc1 += h0.y*a0;
    }
    float o0 = acc0 + bias[2*lane];
    float o1 = acc1 + bias[2*lane + 1];
    o0 = o0 > 0.f ? o0 : expm1f(o0);
    o1 = o1 > 0.f ? o1 : expm1f(o1);
    float2 o = {o0, o1};
    *(float2*)&xout[(size_t)d*HIDDEN + 2*lane] = o;
}

// ---- total_score[b] = dot(x[target[b]], lin3_W) + lin3_b ----
__global__ void score_kernel(const float* __restrict__ x, const int* __restrict__ tgt,
                             const float* __restrict__ w, const float* __restrict__ b,
                             float* __restrict__ scores, float* __restrict__ dout){
    int bb = blockIdx.x, t = threadIdx.x;   // 64 threads
    const float* row = x + (size_t)tgt[bb]*HIDDEN;
    float v = row[t]*w[t] + row[t + 64]*w[t + 64];
    #pragma unroll
    for (int m = 32; m >= 1; m >>= 1) v += __shfl_xor(v, m);
    if (t == 0){
        float sc = v + b[0];
        scores[bb] = sc;
        dout[bb]   = sc;
    }
}

// ---- loss = mean(relu(1 - (pos - neg))) ----
__global__ void loss_kernel(const float* __restrict__ scores, float* __restrict__ dout){
    int t = threadIdx.x;
    float v = 0.f;
    if (t < 32){
        float dlt = 1.0f - (scores[t] - scores[t + 32]);
        v = dlt > 0.f ? dlt : 0.f;
    }
    #pragma unroll
    for (int m = 32; m >= 1; m >>= 1) v += __shfl_xor(v, m);
    if (t == 0) dout[BATCH] = v * (1.0f/32.0f);
}

extern "C" void kernel_launch(void* const* d_in, const int* in_sizes, int n_in,
                              void* d_out, int out_size, void* d_ws, size_t ws_size,
                              hipStream_t stream) {
    const float* word   = (const float*)d_in[0];
    const int*   ei     = (const int*)  d_in[1];
    const int*   tgt    = (const int*)  d_in[2];
    const float* lin1W  = (const float*)d_in[4];
    const float* lin1b  = (const float*)d_in[5];
    const float* gatW   = (const float*)d_in[6];
    const float* attS   = (const float*)d_in[7];
    const float* attD   = (const float*)d_in[8];
    const float* gatB   = (const float*)d_in[9];
    const float* lin3W  = (const float*)d_in[10];
    const float* lin3b  = (const float*)d_in[11];

    char* ws = (char*)d_ws;
    size_t off = 0;
    float* x       = (float*)(ws + off); off += (size_t)N_NODES*HIDDEN*4;
    float* h       = (float*)(ws + off); off += (size_t)N_NODES*HIDDEN*4;
    float* a_s     = (float*)(ws + off); off += (size_t)N_NODES*HEADS*4;
    float* a_d     = (float*)(ws + off); off += (size_t)N_NODES*HEADS*4;
    int*   deg     = (int*)(ws + off);   off += (size_t)(N_NODES + 16)*4;
    int*   scantmp = (int*)(ws + off);   off += (size_t)(N_NODES + 16)*4;
    int*   bsums   = (int*)(ws + off);   off += 1024;
    int*   row_ptr = (int*)(ws + off);   off += (size_t)(N_NODES + 16)*4;
    int*   cursor  = (int*)(ws + off);   off += (size_t)(N_NODES + 16)*4;
    int*   col_src = (int*)(ws + off);   off += (size_t)E_TOT*4;
    float* Wa      = (float*)(ws + off); off += 128*16*4;
    float* scores  = (float*)(ws + off); off += 256;

    const int EB  = (E_TOT + 255)/256;
    const int NB  = (N_NODES + 255)/256;
    const int SB  = (N_NODES + 1023)/1024;
    const int GB  = (N_NODES + 63)/64;      // mfma gemm blocks

    // ---- CSR build (once) ----
    hipMemsetAsync(deg, 0, (size_t)N_NODES*4, stream);
    deg_kernel       <<<EB, 256, 0, stream>>>(ei, deg);
    scan_block_kernel<<<SB, 1024, 0, stream>>>(deg, scantmp, bsums);
    scan_sums_kernel <<<1, 64, 0, stream>>>(bsums, SB);
    scan_add_kernel  <<<NB, 256, 0, stream>>>(scantmp, bsums, row_ptr, cursor);
    scatter_kernel   <<<EB, 256, 0, stream>>>(ei, cursor, col_src);

    // ---- lin1: x = word @ lin1_W + b ----
    mfma_gemm_kernel<INPUT, 320, 8, true, false><<<GB, 256, 0, stream>>>(
        word, lin1W, nullptr, lin1b, x, nullptr, nullptr, N_NODES);

    for (int L = 0; L < 2; L++){
        const float* W = gatW + (size_t)L*HIDDEN*HIDDEN;
        wa_kernel<<<1, 128, 0, stream>>>(W, attS + L*HEADS*HEAD_DIM,
                                         attD + L*HEADS*HEAD_DIM, Wa);
        mfma_gemm_kernel<HIDDEN, 128, 9, false, true><<<GB, 256, 0, stream>>>(
            x, W, Wa, nullptr, h, a_s, a_d, N_NODES);
        gat_aggregate_kernel<<<(N_NODES + 3)/4, 256, 0, stream>>>(
            row_ptr, col_src, h, a_s, a_d, gatB + L*HIDDEN, x);
    }

    score_kernel<<<BATCH, 64, 0, stream>>>(x, tgt, lin3W, lin3b, scores, (float*)d_out);
    loss_kernel <<<1, 64, 0, stream>>>(scores, (float*)d_out);
}

// Round 4
// 339.461 us; speedup vs baseline: 3.4774x; 1.6198x over previous
//
#include <hip/hip_runtime.h>
#include <math.h>

#define N_NODES 50000
#define N_EDGESI 800000
#define E_TOT   850000      // + self loops
#define HIDDEN  128
#define HEADS   8
#define HEAD_DIM 16
#define INPUT   300
#define BATCH   64

typedef __bf16 bf16_t;
typedef bf16_t bf16x8 __attribute__((ext_vector_type(8)));
typedef float  f32x4  __attribute__((ext_vector_type(4)));

__device__ __forceinline__ void edge_sd(int e, const int* __restrict__ ei, int& s, int& d){
    if (e < N_EDGESI){ s = ei[e]; d = ei[N_EDGESI + e]; }
    else { s = e - N_EDGESI; d = s; }
}
__device__ __forceinline__ float bflo(unsigned u){ return __uint_as_float(u << 16); }
__device__ __forceinline__ float bfhi(unsigned u){ return __uint_as_float(u & 0xffff0000u); }

// ===== pack B (fp32 -> fragment-ready bf16 hi/lo planes), runs once =====
// layout: plane[(k/8)*NCOL*8 + col*8 + (k%8)]
template<int K_REAL, int K_PAD, int NCOL>
__global__ void pack_b_kernel(const float* __restrict__ B128, const float* __restrict__ Wa,
                              bf16_t* __restrict__ bHi, bf16_t* __restrict__ bLo){
    int idx = blockIdx.x*256 + threadIdx.x;
    if (idx >= K_PAD*NCOL) return;
    int k = idx / NCOL, col = idx % NCOL;
    float v = 0.f;
    if (k < K_REAL) v = (col < 128) ? B128[k*128 + col] : Wa[k*16 + (col - 128)];
    bf16_t hi = (bf16_t)v;
    bf16_t lo = (bf16_t)(v - (float)hi);
    int o = ((k >> 3)*NCOL + col)*8 + (k & 7);
    bHi[o] = hi; bLo[o] = lo;
}

// ===== MFMA GEMM, fp32 accuracy via bf16 hi/lo split, no LDS =====
// one wave = 16 rows x NCOL cols.  A fp32 from global, B packed bf16 planes.
template<int K_REAL, int NT, bool BIAS_EPI, bool ALPHA>
__global__ __launch_bounds__(256)
void mfma_gemm2_kernel(const float* __restrict__ A, const bf16_t* __restrict__ bHi,
                       const bf16_t* __restrict__ bLo, const float* __restrict__ bias,
                       float* __restrict__ outF, bf16_t* __restrict__ outH,
                       float* __restrict__ asrc_out, float* __restrict__ adst_out, int M)
{
    constexpr int NCOL   = NT * 16;
    constexpr int KSTEPS = (K_REAL + 31) / 32;
    int tid = threadIdx.x, lane = tid & 63, w = tid >> 6;
    int l15 = lane & 15, lg = lane >> 4;
    int m0 = (blockIdx.x*4 + w) * 16;
    if (m0 >= M) return;
    const float* arow = A + (size_t)(m0 + l15)*K_REAL;

    f32x4 acc[NT];
    #pragma unroll
    for (int c = 0; c < NT; c++) acc[c] = (f32x4){0.f,0.f,0.f,0.f};

    for (int ks = 0; ks < KSTEPS; ks++){
        int k0 = ks*32 + lg*8;
        float4 va = {0.f,0.f,0.f,0.f}, vb = {0.f,0.f,0.f,0.f};
        if (k0 + 3 < K_REAL) va = *(const float4*)&arow[k0];
        if (k0 + 7 < K_REAL) vb = *(const float4*)&arow[k0 + 4];
        float f[8] = {va.x, va.y, va.z, va.w, vb.x, vb.y, vb.z, vb.w};
        bf16x8 ah, al;
        #pragma unroll
        for (int q = 0; q < 8; q++){
            bf16_t hi = (bf16_t)f[q];
            ah[q] = hi;
            al[q] = (bf16_t)(f[q] - (float)hi);
        }
        int g = ks*4 + lg;
        const bf16_t* bh_base = bHi + ((size_t)g*NCOL + l15)*8;
        const bf16_t* bl_base = bLo + ((size_t)g*NCOL + l15)*8;
        #pragma unroll
        for (int c = 0; c < NT; c++){
            bf16x8 bh = *(const bf16x8*)&bh_base[c*128];   // c*16 cols * 8
            bf16x8 bl = *(const bf16x8*)&bl_base[c*128];
            acc[c] = __builtin_amdgcn_mfma_f32_16x16x32_bf16(ah, bh, acc[c], 0,0,0);
            acc[c] = __builtin_amdgcn_mfma_f32_16x16x32_bf16(ah, bl, acc[c], 0,0,0);
            acc[c] = __builtin_amdgcn_mfma_f32_16x16x32_bf16(al, bh, acc[c], 0,0,0);
        }
    }

    // epilogue: D col = lane&15 (within tile), row = (lane>>4)*4 + reg
    #pragma unroll
    for (int c = 0; c < 8; c++){
        int col = c*16 + l15;
        float bv = BIAS_EPI ? bias[col] : 0.f;
        #pragma unroll
        for (int r = 0; r < 4; r++){
            int m = m0 + lg*4 + r;
            if (!ALPHA) outF[(size_t)m*128 + col] = acc[c][r] + bv;
            else        outH[(size_t)m*128 + col] = (bf16_t)acc[c][r];
        }
    }
    if (ALPHA){
        #pragma unroll
        for (int r = 0; r < 4; r++){
            int m = m0 + lg*4 + r;
            float v = acc[8][r];
            if (l15 < 8) asrc_out[m*8 + l15]       = v;
            else         adst_out[m*8 + (l15 - 8)] = v;
        }
    }
}

// ---- Wa[k][j] = sum_d W[k][j*16+d]*a[j][d]  (j<8: src, j>=8: dst) ----
__global__ void wa_kernel(const float* __restrict__ W, const float* __restrict__ as,
                          const float* __restrict__ ad, float* __restrict__ Wa){
    int k = threadIdx.x;   // 128
    #pragma unroll
    for (int j = 0; j < 8; j++){
        float s1 = 0.f, s2 = 0.f;
        #pragma unroll
        for (int d = 0; d < 16; d++){
            float wv = W[k*128 + j*16 + d];
            s1 += wv * as[j*16 + d];
            s2 += wv * ad[j*16 + d];
        }
        Wa[k*16 + j]     = s1;
        Wa[k*16 + 8 + j] = s2;
    }
}

// ======================= CSR build (once) =======================
__global__ void deg_kernel(const int* __restrict__ ei, int* __restrict__ deg){
    int e = blockIdx.x*256 + threadIdx.x;
    if (e >= E_TOT) return;
    int s, d; edge_sd(e, ei, s, d);
    atomicAdd(&deg[d], 1);
}

__global__ void scan_block_kernel(const int* __restrict__ deg, int* __restrict__ scanout,
                                  int* __restrict__ blocksums){
    __shared__ int buf[1024];
    int gid = blockIdx.x*1024 + threadIdx.x;
    int v = (gid < N_NODES) ? deg[gid] : 0;
    buf[threadIdx.x] = v;
    __syncthreads();
    for (int off = 1; off < 1024; off <<= 1){
        int t = (threadIdx.x >= off) ? buf[threadIdx.x - off] : 0;
        __syncthreads();
        buf[threadIdx.x] += t;
        __syncthreads();
    }
    if (gid < N_NODES) scanout[gid] = buf[threadIdx.x] - v;   // exclusive
    if (threadIdx.x == 1023) blocksums[blockIdx.x] = buf[1023];
}

__global__ void scan_sums_kernel(int* __restrict__ blocksums, int nb){
    if (threadIdx.x == 0){
        int acc = 0;
        for (int i = 0; i < nb; i++){ int v = blocksums[i]; blocksums[i] = acc; acc += v; }
    }
}

__global__ void scan_add_kernel(const int* __restrict__ scanout, const int* __restrict__ blocksums,
                                int* __restrict__ row_ptr, int* __restrict__ cursor){
    int i = blockIdx.x*256 + threadIdx.x;
    if (i < N_NODES){
        int v = scanout[i] + blocksums[i >> 10];
        row_ptr[i] = v;
        cursor[i]  = v;
    }
    if (i == 0) row_ptr[N_NODES] = E_TOT;
}

__global__ void scatter_kernel(const int* __restrict__ ei, int* __restrict__ cursor,
                               int* __restrict__ col_src){
    int e = blockIdx.x*256 + threadIdx.x;
    if (e >= E_TOT) return;
    int s, d; edge_sd(e, ei, s, d);
    int pos = atomicAdd(&cursor[d], 1);
    col_src[pos] = s;
}

// ===== fused per-dst softmax + aggregate + bias + ELU: one wave per node =====
__global__ __launch_bounds__(256)
void gat_aggregate_kernel(const int* __restrict__ row_ptr, const int* __restrict__ col_src,
                          const unsigned short* __restrict__ H, const float* __restrict__ a_s,
                          const float* __restrict__ a_d, const float* __restrict__ bias,
                          float* __restrict__ xout){
    __shared__ float alds[4][8][65];
    int wave = threadIdx.x >> 6;
    int lane = threadIdx.x & 63;
    int d = blockIdx.x*4 + wave;
    if (d >= N_NODES) return;
    int start = row_ptr[d], end = row_ptr[d + 1];
    int deg = end - start;
    int hme = lane >> 3;

    float ad_[8];
    {
        float4 t0 = *(const float4*)&a_d[d*8];
        float4 t1 = *(const float4*)&a_d[d*8 + 4];
        ad_[0]=t0.x; ad_[1]=t0.y; ad_[2]=t0.z; ad_[3]=t0.w;
        ad_[4]=t1.x; ad_[5]=t1.y; ad_[6]=t1.z; ad_[7]=t1.w;
    }

    float acc0 = 0.f, acc1 = 0.f;
    unsigned hoff = 2u*lane;

    if (deg <= 64){
        bool act = lane < deg;
        int sreg = 0;
        float lg[8];
        float m[8];
        #pragma unroll
        for (int h = 0; h < 8; h++) m[h] = -1e30f;
        if (act){
            sreg = col_src[start + lane];
            float4 s0 = *(const float4*)&a_s[sreg*8];
            float4 s1 = *(const float4*)&a_s[sreg*8 + 4];
            float as_[8] = {s0.x,s0.y,s0.z,s0.w,s1.x,s1.y,s1.z,s1.w};
            #pragma unroll
            for (int h = 0; h < 8; h++){
                float v = as_[h] + ad_[h];
                v = v > 0.f ? v : 0.2f*v;
                lg[h] = v; m[h] = v;
            }
        }
        #pragma unroll
        for (int h = 0; h < 8; h++){
            float v = m[h];
            #pragma unroll
            for (int off = 32; off >= 1; off >>= 1) v = fmaxf(v, __shfl_xor(v, off));
            m[h] = v;
        }
        float ssum[8];
        #pragma unroll
        for (int h = 0; h < 8; h++){
            float e = act ? __expf(lg[h] - m[h]) : 0.f;
            alds[wave][h][lane] = e;
            ssum[h] = e;
        }
        #pragma unroll
        for (int h = 0; h < 8; h++){
            float v = ssum[h];
            #pragma unroll
            for (int off = 32; off >= 1; off >>= 1) v += __shfl_xor(v, off);
            ssum[h] = v;
        }
        float dh = 1.0f / ssum[hme];
        const float* al_row = &alds[wave][hme][0];

        int p = 0;
        for (; p + 4 <= deg; p += 4){
            int s0 = __shfl(sreg, p+0), s1 = __shfl(sreg, p+1);
            int s2 = __shfl(sreg, p+2), s3 = __shfl(sreg, p+3);
            unsigned g0 = *(const unsigned*)&H[(size_t)s0*128 + hoff];
            unsigned g1 = *(const unsigned*)&H[(size_t)s1*128 + hoff];
            unsigned g2 = *(const unsigned*)&H[(size_t)s2*128 + hoff];
            unsigned g3 = *(const unsigned*)&H[(size_t)s3*128 + hoff];
            float a0 = al_row[p+0]*dh, a1 = al_row[p+1]*dh;
            float a2 = al_row[p+2]*dh, a3 = al_row[p+3]*dh;
            acc0 += bflo(g0)*a0 + bflo(g1)*a1 + bflo(g2)*a2 + bflo(g3)*a3;
            acc1 += bfhi(g0)*a0 + bfhi(g1)*a1 + bfhi(g2)*a2 + bfhi(g3)*a3;
        }
        for (; p < deg; p++){
            int s0 = __shfl(sreg, p);
            unsigned g0 = *(const unsigned*)&H[(size_t)s0*128 + hoff];
            float a0 = al_row[p]*dh;
            acc0 += bflo(g0)*a0;
            acc1 += bfhi(g0)*a0;
        }
    } else {
        // rare fallback: deg > 64, full recompute
        float m[8];
        #pragma unroll
        for (int h = 0; h < 8; h++) m[h] = -1e30f;
        for (int p = start + lane; p < end; p += 64){
            int s = col_src[p];
            #pragma unroll
            for (int h = 0; h < 8; h++){
                float v = a_s[s*8 + h] + ad_[h];
                v = v > 0.f ? v : 0.2f*v;
                m[h] = fmaxf(m[h], v);
            }
        }
        #pragma unroll
        for (int h = 0; h < 8; h++){
            float v = m[h];
            #pragma unroll
            for (int off = 32; off >= 1; off >>= 1) v = fmaxf(v, __shfl_xor(v, off));
            m[h] = v;
        }
        float ssum[8];
        #pragma unroll
        for (int h = 0; h < 8; h++) ssum[h] = 0.f;
        for (int p = start + lane; p < end; p += 64){
            int s = col_src[p];
            #pragma unroll
            for (int h = 0; h < 8; h++){
                float v = a_s[s*8 + h] + ad_[h];
                v = v > 0.f ? v : 0.2f*v;
                ssum[h] += __expf(v - m[h]);
            }
        }
        #pragma unroll
        for (int h = 0; h < 8; h++){
            float v = ssum[h];
            #pragma unroll
            for (int off = 32; off >= 1; off >>= 1) v += __shfl_xor(v, off);
            ssum[h] = v;
        }
        float dh = 1.0f/ssum[hme], mh = m[hme], adh = ad_[hme];
        for (int p = start; p < end; p++){
            int s = col_src[p];
            float v = a_s[s*8 + hme] + adh;
            v = v > 0.f ? v : 0.2f*v;
            float a = __expf(v - mh)*dh;
            unsigned g = *(const unsigned*)&H[(size_t)s*128 + hoff];
            acc0 += bflo(g)*a;
            acc1 += bfhi(g)*a;
        }
    }

    float o0 = acc0 + bias[2*lane];
    float o1 = acc1 + bias[2*lane + 1];
    o0 = o0 > 0.f ? o0 : expm1f(o0);
    o1 = o1 > 0.f ? o1 : expm1f(o1);
    float2 o = {o0, o1};
    *(float2*)&xout[(size_t)d*HIDDEN + 2*lane] = o;
}

// ---- total_score[b] = dot(x[target[b]], lin3_W) + lin3_b ----
__global__ void score_kernel(const float* __restrict__ x, const int* __restrict__ tgt,
                             const float* __restrict__ w, const float* __restrict__ b,
                             float* __restrict__ scores, float* __restrict__ dout){
    int bb = blockIdx.x, t = threadIdx.x;   // 64 threads
    const float* row = x + (size_t)tgt[bb]*HIDDEN;
    float v = row[t]*w[t] + row[t + 64]*w[t + 64];
    #pragma unroll
    for (int m = 32; m >= 1; m >>= 1) v += __shfl_xor(v, m);
    if (t == 0){
        float sc = v + b[0];
        scores[bb] = sc;
        dout[bb]   = sc;
    }
}

// ---- loss = mean(relu(1 - (pos - neg))) ----
__global__ void loss_kernel(const float* __restrict__ scores, float* __restrict__ dout){
    int t = threadIdx.x;
    float v = 0.f;
    if (t < 32){
        float dlt = 1.0f - (scores[t] - scores[t + 32]);
        v = dlt > 0.f ? dlt : 0.f;
    }
    #pragma unroll
    for (int m = 32; m >= 1; m >>= 1) v += __shfl_xor(v, m);
    if (t == 0) dout[BATCH] = v * (1.0f/32.0f);
}

extern "C" void kernel_launch(void* const* d_in, const int* in_sizes, int n_in,
                              void* d_out, int out_size, void* d_ws, size_t ws_size,
                              hipStream_t stream) {
    const float* word   = (const float*)d_in[0];
    const int*   ei     = (const int*)  d_in[1];
    const int*   tgt    = (const int*)  d_in[2];
    const float* lin1W  = (const float*)d_in[4];
    const float* lin1b  = (const float*)d_in[5];
    const float* gatW   = (const float*)d_in[6];
    const float* attS   = (const float*)d_in[7];
    const float* attD   = (const float*)d_in[8];
    const float* gatB   = (const float*)d_in[9];
    const float* lin3W  = (const float*)d_in[10];
    const float* lin3b  = (const float*)d_in[11];

    char* ws = (char*)d_ws;
    size_t off = 0;
    float*   x       = (float*)(ws + off);   off += (size_t)N_NODES*HIDDEN*4;
    bf16_t*  Hb      = (bf16_t*)(ws + off);  off += (size_t)N_NODES*HIDDEN*2;
    float*   a_s     = (float*)(ws + off);   off += (size_t)N_NODES*HEADS*4;
    float*   a_d     = (float*)(ws + off);   off += (size_t)N_NODES*HEADS*4;
    int*     deg     = (int*)(ws + off);     off += (size_t)(N_NODES + 16)*4;
    int*     scantmp = (int*)(ws + off);     off += (size_t)(N_NODES + 16)*4;
    int*     bsums   = (int*)(ws + off);     off += 1024;
    int*     row_ptr = (int*)(ws + off);     off += (size_t)(N_NODES + 16)*4;
    int*     cursor  = (int*)(ws + off);     off += (size_t)(N_NODES + 16)*4;
    int*     col_src = (int*)(ws + off);     off += (size_t)E_TOT*4;
    bf16_t*  b1Hi    = (bf16_t*)(ws + off);  off += (size_t)320*128*2;
    bf16_t*  b1Lo    = (bf16_t*)(ws + off);  off += (size_t)320*128*2;
    bf16_t*  b2Hi    = (bf16_t*)(ws + off);  off += (size_t)128*144*2;
    bf16_t*  b2Lo    = (bf16_t*)(ws + off);  off += (size_t)128*144*2;
    float*   Wa      = (float*)(ws + off);   off += 128*16*4;
    float*   scores  = (float*)(ws + off);   off += 256;

    const int EB = (E_TOT + 255)/256;
    const int NB = (N_NODES + 255)/256;
    const int SB = (N_NODES + 1023)/1024;
    const int GB = ((N_NODES + 15)/16 + 3)/4;     // 782 gemm blocks

    // ---- CSR build (once) ----
    hipMemsetAsync(deg, 0, (size_t)N_NODES*4, stream);
    deg_kernel       <<<EB, 256, 0, stream>>>(ei, deg);
    scan_block_kernel<<<SB, 1024, 0, stream>>>(deg, scantmp, bsums);
    scan_sums_kernel <<<1, 64, 0, stream>>>(bsums, SB);
    scan_add_kernel  <<<NB, 256, 0, stream>>>(scantmp, bsums, row_ptr, cursor);
    scatter_kernel   <<<EB, 256, 0, stream>>>(ei, cursor, col_src);

    // ---- lin1: x = word @ lin1_W + b ----
    pack_b_kernel<INPUT, 320, 128><<<(320*128 + 255)/256, 256, 0, stream>>>(
        lin1W, nullptr, b1Hi, b1Lo);
    mfma_gemm2_kernel<INPUT, 8, true, false><<<GB, 256, 0, stream>>>(
        word, b1Hi, b1Lo, lin1b, x, nullptr, nullptr, nullptr, N_NODES);

    for (int L = 0; L < 2; L++){
        const float* W = gatW + (size_t)L*HIDDEN*HIDDEN;
        wa_kernel<<<1, 128, 0, stream>>>(W, attS + L*HEADS*HEAD_DIM,
                                         attD + L*HEADS*HEAD_DIM, Wa);
        pack_b_kernel<HIDDEN, 128, 144><<<(128*144 + 255)/256, 256, 0, stream>>>(
            W, Wa, b2Hi, b2Lo);
        mfma_gemm2_kernel<HIDDEN, 9, false, true><<<GB, 256, 0, stream>>>(
            x, b2Hi, b2Lo, nullptr, nullptr, Hb, a_s, a_d, N_NODES);
        gat_aggregate_kernel<<<(N_NODES + 3)/4, 256, 0, stream>>>(
            row_ptr, col_src, (const unsigned short*)Hb, a_s, a_d, gatB + L*HIDDEN, x);
    }

    score_kernel<<<BATCH, 64, 0, stream>>>(x, tgt, lin3W, lin3b, scores, (float*)d_out);
    loss_kernel <<<1, 64, 0, stream>>>(scores, (float*)d_out);
}

// Round 5
// 283.149 us; speedup vs baseline: 4.1690x; 1.1989x over previous
//
#include <hip/hip_runtime.h>
#include <math.h>

#define N_NODES 50000
#define N_EDGESI 800000
#define E_TOT   850000      // + self loops
#define HIDDEN  128
#define HEADS   8
#define HEAD_DIM 16
#define INPUT   300
#define BATCH   64

typedef __bf16 bf16_t;
typedef bf16_t bf16x8 __attribute__((ext_vector_type(8)));
typedef float  f32x4  __attribute__((ext_vector_type(4)));

__device__ __forceinline__ void edge_sd(int e, const int* __restrict__ ei, int& s, int& d){
    if (e < N_EDGESI){ s = ei[e]; d = ei[N_EDGESI + e]; }
    else { s = e - N_EDGESI; d = s; }
}
__device__ __forceinline__ float bflo(unsigned u){ return __uint_as_float(u << 16); }
__device__ __forceinline__ float bfhi(unsigned u){ return __uint_as_float(u & 0xffff0000u); }

// ===== pack B (fp32 -> fragment-ready bf16 hi/lo planes), runs once =====
// layout: plane[(k/8)*NCOL*8 + col*8 + (k%8)]
template<int K_REAL, int K_PAD, int NCOL>
__global__ void pack_b_kernel(const float* __restrict__ B128, const float* __restrict__ Wa,
                              bf16_t* __restrict__ bHi, bf16_t* __restrict__ bLo){
    int idx = blockIdx.x*256 + threadIdx.x;
    if (idx >= K_PAD*NCOL) return;
    int k = idx / NCOL, col = idx % NCOL;
    float v = 0.f;
    if (k < K_REAL) v = (col < 128) ? B128[k*128 + col] : Wa[k*16 + (col - 128)];
    bf16_t hi = (bf16_t)v;
    bf16_t lo = (bf16_t)(v - (float)hi);
    int o = ((k >> 3)*NCOL + col)*8 + (k & 7);
    bHi[o] = hi; bLo[o] = lo;
}

// ===== MFMA GEMM, fp32 accuracy via bf16 hi/lo split, no LDS =====
template<int K_REAL, int NT, bool BIAS_EPI, bool ALPHA>
__global__ __launch_bounds__(256)
void mfma_gemm2_kernel(const float* __restrict__ A, const bf16_t* __restrict__ bHi,
                       const bf16_t* __restrict__ bLo, const float* __restrict__ bias,
                       float* __restrict__ outF, bf16_t* __restrict__ outH,
                       float* __restrict__ asrc_out, float* __restrict__ adst_out, int M)
{
    constexpr int NCOL   = NT * 16;
    constexpr int KSTEPS = (K_REAL + 31) / 32;
    int tid = threadIdx.x, lane = tid & 63, w = tid >> 6;
    int l15 = lane & 15, lg = lane >> 4;
    int m0 = (blockIdx.x*4 + w) * 16;
    if (m0 >= M) return;
    const float* arow = A + (size_t)(m0 + l15)*K_REAL;

    f32x4 acc[NT];
    #pragma unroll
    for (int c = 0; c < NT; c++) acc[c] = (f32x4){0.f,0.f,0.f,0.f};

    for (int ks = 0; ks < KSTEPS; ks++){
        int k0 = ks*32 + lg*8;
        float4 va = {0.f,0.f,0.f,0.f}, vb = {0.f,0.f,0.f,0.f};
        if (k0 + 3 < K_REAL) va = *(const float4*)&arow[k0];
        if (k0 + 7 < K_REAL) vb = *(const float4*)&arow[k0 + 4];
        float f[8] = {va.x, va.y, va.z, va.w, vb.x, vb.y, vb.z, vb.w};
        bf16x8 ah, al;
        #pragma unroll
        for (int q = 0; q < 8; q++){
            bf16_t hi = (bf16_t)f[q];
            ah[q] = hi;
            al[q] = (bf16_t)(f[q] - (float)hi);
        }
        int g = ks*4 + lg;
        const bf16_t* bh_base = bHi + ((size_t)g*NCOL + l15)*8;
        const bf16_t* bl_base = bLo + ((size_t)g*NCOL + l15)*8;
        #pragma unroll
        for (int c = 0; c < NT; c++){
            bf16x8 bh = *(const bf16x8*)&bh_base[c*128];
            bf16x8 bl = *(const bf16x8*)&bl_base[c*128];
            acc[c] = __builtin_amdgcn_mfma_f32_16x16x32_bf16(ah, bh, acc[c], 0,0,0);
            acc[c] = __builtin_amdgcn_mfma_f32_16x16x32_bf16(ah, bl, acc[c], 0,0,0);
            acc[c] = __builtin_amdgcn_mfma_f32_16x16x32_bf16(al, bh, acc[c], 0,0,0);
        }
    }

    #pragma unroll
    for (int c = 0; c < 8; c++){
        int col = c*16 + l15;
        float bv = BIAS_EPI ? bias[col] : 0.f;
        #pragma unroll
        for (int r = 0; r < 4; r++){
            int m = m0 + lg*4 + r;
            if (!ALPHA) outF[(size_t)m*128 + col] = acc[c][r] + bv;
            else        outH[(size_t)m*128 + col] = (bf16_t)acc[c][r];
        }
    }
    if (ALPHA){
        #pragma unroll
        for (int r = 0; r < 4; r++){
            int m = m0 + lg*4 + r;
            float v = acc[8][r];
            if (l15 < 8) asrc_out[m*8 + l15]       = v;
            else         adst_out[m*8 + (l15 - 8)] = v;
        }
    }
}

// ---- Wa[k][j] = sum_d W[k][j*16+d]*a[j][d]  (j<8: src, j>=8: dst) ----
__global__ void wa_kernel(const float* __restrict__ W, const float* __restrict__ as,
                          const float* __restrict__ ad, float* __restrict__ Wa){
    int k = threadIdx.x;   // 128
    #pragma unroll
    for (int j = 0; j < 8; j++){
        float s1 = 0.f, s2 = 0.f;
        #pragma unroll
        for (int d = 0; d < 16; d++){
            float wv = W[k*128 + j*16 + d];
            s1 += wv * as[j*16 + d];
            s2 += wv * ad[j*16 + d];
        }
        Wa[k*16 + j]     = s1;
        Wa[k*16 + 8 + j] = s2;
    }
}

// ======================= CSR build (once) =======================
__global__ void deg_kernel(const int* __restrict__ ei, int* __restrict__ deg){
    int e = blockIdx.x*256 + threadIdx.x;
    if (e >= E_TOT) return;
    int s, d; edge_sd(e, ei, s, d);
    atomicAdd(&deg[d], 1);
}

__global__ void scan_block_kernel(const int* __restrict__ deg, int* __restrict__ scanout,
                                  int* __restrict__ blocksums){
    __shared__ int buf[1024];
    int gid = blockIdx.x*1024 + threadIdx.x;
    int v = (gid < N_NODES) ? deg[gid] : 0;
    buf[threadIdx.x] = v;
    __syncthreads();
    for (int off = 1; off < 1024; off <<= 1){
        int t = (threadIdx.x >= off) ? buf[threadIdx.x - off] : 0;
        __syncthreads();
        buf[threadIdx.x] += t;
        __syncthreads();
    }
    if (gid < N_NODES) scanout[gid] = buf[threadIdx.x] - v;   // exclusive
    if (threadIdx.x == 1023) blocksums[blockIdx.x] = buf[1023];
}

// wave-parallel exclusive scan of <=64 block sums
__global__ void scan_sums_kernel(int* __restrict__ blocksums, int nb){
    int t = threadIdx.x;   // 64
    int orig = (t < nb) ? blocksums[t] : 0;
    int v = orig;
    #pragma unroll
    for (int off = 1; off < 64; off <<= 1){
        int u = __shfl_up(v, off);
        if (t >= off) v += u;
    }
    if (t < nb) blocksums[t] = v - orig;   // exclusive
}

__global__ void scan_add_kernel(const int* __restrict__ scanout, const int* __restrict__ blocksums,
                                int* __restrict__ row_ptr, int* __restrict__ cursor){
    int i = blockIdx.x*256 + threadIdx.x;
    if (i < N_NODES){
        int v = scanout[i] + blocksums[i >> 10];
        row_ptr[i] = v;
        cursor[i]  = v;
    }
    if (i == 0) row_ptr[N_NODES] = E_TOT;
}

__global__ void scatter_kernel(const int* __restrict__ ei, int* __restrict__ cursor,
                               int* __restrict__ col_src){
    int e = blockIdx.x*256 + threadIdx.x;
    if (e >= E_TOT) return;
    int s, d; edge_sd(e, ei, s, d);
    int pos = atomicAdd(&cursor[d], 1);
    col_src[pos] = s;
}

// ===== fused per-dst softmax + aggregate + bias + ELU: one wave per node =====
// no max-subtraction (softmax shift-invariant; logits O(1), clamped at 70)
__global__ __launch_bounds__(256)
void gat_aggregate_kernel(const int* __restrict__ row_ptr, const int* __restrict__ col_src,
                          const unsigned short* __restrict__ H, const float* __restrict__ a_s,
                          const float* __restrict__ a_d, const float* __restrict__ bias,
                          float* __restrict__ xout){
    __shared__ float alds[4][8][65];
    int wave = threadIdx.x >> 6;
    int lane = threadIdx.x & 63;
    int d = blockIdx.x*4 + wave;
    if (d >= N_NODES) return;
    int start = row_ptr[d], end = row_ptr[d + 1];
    int deg = end - start;                 // >= 1 (self loop)
    int hme = lane >> 3, seg = lane & 7;

    float ad_[8];
    {
        float4 t0 = *(const float4*)&a_d[d*8];
        float4 t1 = *(const float4*)&a_d[d*8 + 4];
        ad_[0]=t0.x; ad_[1]=t0.y; ad_[2]=t0.z; ad_[3]=t0.w;
        ad_[4]=t1.x; ad_[5]=t1.y; ad_[6]=t1.z; ad_[7]=t1.w;
    }

    float acc0 = 0.f, acc1 = 0.f, dh;
    unsigned hoff = 2u*lane;

    if (deg <= 64){
        bool act = lane < deg;
        int sreg = 0;
        float e[8];
        #pragma unroll
        for (int h = 0; h < 8; h++) e[h] = 0.f;
        if (act){
            sreg = col_src[start + lane];
            float4 s0 = *(const float4*)&a_s[sreg*8];
            float4 s1 = *(const float4*)&a_s[sreg*8 + 4];
            float as_[8] = {s0.x,s0.y,s0.z,s0.w,s1.x,s1.y,s1.z,s1.w};
            #pragma unroll
            for (int h = 0; h < 8; h++){
                float v = as_[h] + ad_[h];
                v = v > 0.f ? v : 0.2f*v;
                e[h] = __expf(fminf(v, 70.f));
            }
        }
        #pragma unroll
        for (int h = 0; h < 8; h++) alds[wave][h][lane] = e[h];

        // transpose-reduce: lane (hme,seg) sums cols seg*8..+7 of row hme,
        // then 3-level butterfly within the 8-lane group
        const float* row = &alds[wave][hme][0];
        float s = 0.f;
        #pragma unroll
        for (int j = 0; j < 8; j++) s += row[seg*8 + j];
        s += __shfl_xor(s, 1); s += __shfl_xor(s, 2); s += __shfl_xor(s, 4);
        dh = 1.0f / s;

        int p = 0;
        for (; p + 4 <= deg; p += 4){
            int s0 = __shfl(sreg, p+0), s1 = __shfl(sreg, p+1);
            int s2 = __shfl(sreg, p+2), s3 = __shfl(sreg, p+3);
            unsigned g0 = *(const unsigned*)&H[(size_t)s0*128 + hoff];
            unsigned g1 = *(const unsigned*)&H[(size_t)s1*128 + hoff];
            unsigned g2 = *(const unsigned*)&H[(size_t)s2*128 + hoff];
            unsigned g3 = *(const unsigned*)&H[(size_t)s3*128 + hoff];
            float a0 = row[p+0], a1 = row[p+1], a2 = row[p+2], a3 = row[p+3];
            acc0 += bflo(g0)*a0 + bflo(g1)*a1 + bflo(g2)*a2 + bflo(g3)*a3;
            acc1 += bfhi(g0)*a0 + bfhi(g1)*a1 + bfhi(g2)*a2 + bfhi(g3)*a3;
        }
        for (; p < deg; p++){
            int s0 = __shfl(sreg, p);
            unsigned g0 = *(const unsigned*)&H[(size_t)s0*128 + hoff];
            float a0 = row[p];
            acc0 += bflo(g0)*a0;
            acc1 += bfhi(g0)*a0;
        }
    } else {
        // rare fallback (deg > 64): group hme strides edges for its head only
        float adh = ad_[hme];
        float s = 0.f;
        for (int p = start + seg; p < end; p += 8){
            int sn = col_src[p];
            float v = a_s[sn*8 + hme] + adh;
            v = v > 0.f ? v : 0.2f*v;
            s += __expf(fminf(v, 70.f));
        }
        s += __shfl_xor(s, 1); s += __shfl_xor(s, 2); s += __shfl_xor(s, 4);
        dh = 1.0f / s;
        for (int p = start; p < end; p++){
            int sn = col_src[p];
            float v = a_s[sn*8 + hme] + adh;
            v = v > 0.f ? v : 0.2f*v;
            float a = __expf(fminf(v, 70.f));
            unsigned g = *(const unsigned*)&H[(size_t)sn*128 + hoff];
            acc0 += bflo(g)*a;
            acc1 += bfhi(g)*a;
        }
    }

    float o0 = acc0*dh + bias[2*lane];
    float o1 = acc1*dh + bias[2*lane + 1];
    o0 = o0 > 0.f ? o0 : expm1f(o0);
    o1 = o1 > 0.f ? o1 : expm1f(o1);
    float2 o = {o0, o1};
    *(float2*)&xout[(size_t)d*HIDDEN + 2*lane] = o;
}

// ---- scores + loss fused: 1 block, 64 threads (one wave per batch... one thread per b) ----
__global__ void head_kernel(const float* __restrict__ x, const int* __restrict__ tgt,
                            const float* __restrict__ w, const float* __restrict__ b,
                            float* __restrict__ dout){
    int t = threadIdx.x;   // 64 = BATCH
    const float* row = x + (size_t)tgt[t]*HIDDEN;
    float v = 0.f;
    #pragma unroll
    for (int c = 0; c < HIDDEN; c += 4){
        float4 xv = *(const float4*)&row[c];
        float4 wv = *(const float4*)&w[c];
        v += xv.x*wv.x + xv.y*wv.y + xv.z*wv.z + xv.w*wv.w;
    }
    float sc = v + b[0];
    dout[t] = sc;
    float neg = __shfl(sc, t + 32);        // valid for t<32
    float dlt = 1.0f - (sc - neg);
    float term = (t < 32) ? (dlt > 0.f ? dlt : 0.f) : 0.f;
    #pragma unroll
    for (int m = 32; m >= 1; m >>= 1) term += __shfl_xor(term, m);
    if (t == 0) dout[BATCH] = term * (1.0f/32.0f);
}

extern "C" void kernel_launch(void* const* d_in, const int* in_sizes, int n_in,
                              void* d_out, int out_size, void* d_ws, size_t ws_size,
                              hipStream_t stream) {
    const float* word   = (const float*)d_in[0];
    const int*   ei     = (const int*)  d_in[1];
    const int*   tgt    = (const int*)  d_in[2];
    const float* lin1W  = (const float*)d_in[4];
    const float* lin1b  = (const float*)d_in[5];
    const float* gatW   = (const float*)d_in[6];
    const float* attS   = (const float*)d_in[7];
    const float* attD   = (const float*)d_in[8];
    const float* gatB   = (const float*)d_in[9];
    const float* lin3W  = (const float*)d_in[10];
    const float* lin3b  = (const float*)d_in[11];

    char* ws = (char*)d_ws;
    size_t off = 0;
    float*   x       = (float*)(ws + off);   off += (size_t)N_NODES*HIDDEN*4;
    bf16_t*  Hb      = (bf16_t*)(ws + off);  off += (size_t)N_NODES*HIDDEN*2;
    float*   a_s     = (float*)(ws + off);   off += (size_t)N_NODES*HEADS*4;
    float*   a_d     = (float*)(ws + off);   off += (size_t)N_NODES*HEADS*4;
    int*     deg     = (int*)(ws + off);     off += (size_t)(N_NODES + 16)*4;
    int*     scantmp = (int*)(ws + off);     off += (size_t)(N_NODES + 16)*4;
    int*     bsums   = (int*)(ws + off);     off += 1024;
    int*     row_ptr = (int*)(ws + off);     off += (size_t)(N_NODES + 16)*4;
    int*     cursor  = (int*)(ws + off);     off += (size_t)(N_NODES + 16)*4;
    int*     col_src = (int*)(ws + off);     off += (size_t)E_TOT*4;
    bf16_t*  b1Hi    = (bf16_t*)(ws + off);  off += (size_t)320*128*2;
    bf16_t*  b1Lo    = (bf16_t*)(ws + off);  off += (size_t)320*128*2;
    bf16_t*  b2Hi    = (bf16_t*)(ws + off);  off += (size_t)128*144*2;
    bf16_t*  b2Lo    = (bf16_t*)(ws + off);  off += (size_t)128*144*2;
    float*   Wa      = (float*)(ws + off);   off += 128*16*4;

    const int EB = (E_TOT + 255)/256;
    const int NB = (N_NODES + 255)/256;
    const int SB = (N_NODES + 1023)/1024;
    const int GB = ((N_NODES + 15)/16 + 3)/4;

    // ---- CSR build (once) ----
    hipMemsetAsync(deg, 0, (size_t)N_NODES*4, stream);
    deg_kernel       <<<EB, 256, 0, stream>>>(ei, deg);
    scan_block_kernel<<<SB, 1024, 0, stream>>>(deg, scantmp, bsums);
    scan_sums_kernel <<<1, 64, 0, stream>>>(bsums, SB);
    scan_add_kernel  <<<NB, 256, 0, stream>>>(scantmp, bsums, row_ptr, cursor);
    scatter_kernel   <<<EB, 256, 0, stream>>>(ei, cursor, col_src);

    // ---- lin1: x = word @ lin1_W + b ----
    pack_b_kernel<INPUT, 320, 128><<<(320*128 + 255)/256, 256, 0, stream>>>(
        lin1W, nullptr, b1Hi, b1Lo);
    mfma_gemm2_kernel<INPUT, 8, true, false><<<GB, 256, 0, stream>>>(
        word, b1Hi, b1Lo, lin1b, x, nullptr, nullptr, nullptr, N_NODES);

    for (int L = 0; L < 2; L++){
        const float* W = gatW + (size_t)L*HIDDEN*HIDDEN;
        wa_kernel<<<1, 128, 0, stream>>>(W, attS + L*HEADS*HEAD_DIM,
                                         attD + L*HEADS*HEAD_DIM, Wa);
        pack_b_kernel<HIDDEN, 128, 144><<<(128*144 + 255)/256, 256, 0, stream>>>(
            W, Wa, b2Hi, b2Lo);
        mfma_gemm2_kernel<HIDDEN, 9, false, true><<<GB, 256, 0, stream>>>(
            x, b2Hi, b2Lo, nullptr, nullptr, Hb, a_s, a_d, N_NODES);
        gat_aggregate_kernel<<<(N_NODES + 3)/4, 256, 0, stream>>>(
            row_ptr, col_src, (const unsigned short*)Hb, a_s, a_d, gatB + L*HIDDEN, x);
    }

    head_kernel<<<1, 64, 0, stream>>>(x, tgt, lin3W, lin3b, (float*)d_out);
}

// Round 6
// 266.846 us; speedup vs baseline: 4.4237x; 1.0611x over previous
//
#include <hip/hip_runtime.h>
#include <math.h>

#define N_NODES 50000
#define N_EDGESI 800000
#define E_TOT   850000      // + self loops
#define HIDDEN  128
#define HEADS   8
#define HEAD_DIM 16
#define INPUT   300
#define BATCH   64
#define NPART   8
#define PSZ     6250        // N_NODES / NPART

typedef __bf16 bf16_t;
typedef bf16_t bf16x8 __attribute__((ext_vector_type(8)));
typedef float  f32x4  __attribute__((ext_vector_type(4)));

__device__ __forceinline__ float bflo(unsigned u){ return __uint_as_float(u << 16); }
__device__ __forceinline__ float bfhi(unsigned u){ return __uint_as_float(u & 0xffff0000u); }

// ===== pack B (fp32 -> fragment-ready bf16 hi/lo planes), runs once =====
template<int K_REAL, int K_PAD, int NCOL>
__global__ void pack_b_kernel(const float* __restrict__ B128, const float* __restrict__ Wa,
                              bf16_t* __restrict__ bHi, bf16_t* __restrict__ bLo){
    int idx = blockIdx.x*256 + threadIdx.x;
    if (idx >= K_PAD*NCOL) return;
    int k = idx / NCOL, col = idx % NCOL;
    float v = 0.f;
    if (k < K_REAL) v = (col < 128) ? B128[k*128 + col] : Wa[k*16 + (col - 128)];
    bf16_t hi = (bf16_t)v;
    bf16_t lo = (bf16_t)(v - (float)hi);
    int o = ((k >> 3)*NCOL + col)*8 + (k & 7);
    bHi[o] = hi; bLo[o] = lo;
}

// ===== MFMA GEMM, fp32 accuracy via bf16 hi/lo split, no LDS =====
template<int K_REAL, int NT, bool BIAS_EPI, bool ALPHA>
__global__ __launch_bounds__(256)
void mfma_gemm2_kernel(const float* __restrict__ A, const bf16_t* __restrict__ bHi,
                       const bf16_t* __restrict__ bLo, const float* __restrict__ bias,
                       float* __restrict__ outF, bf16_t* __restrict__ outH,
                       float* __restrict__ asrc_out, float* __restrict__ adst_out, int M)
{
    constexpr int NCOL   = NT * 16;
    constexpr int KSTEPS = (K_REAL + 31) / 32;
    int tid = threadIdx.x, lane = tid & 63, w = tid >> 6;
    int l15 = lane & 15, lg = lane >> 4;
    int m0 = (blockIdx.x*4 + w) * 16;
    if (m0 >= M) return;
    const float* arow = A + (size_t)(m0 + l15)*K_REAL;

    f32x4 acc[NT];
    #pragma unroll
    for (int c = 0; c < NT; c++) acc[c] = (f32x4){0.f,0.f,0.f,0.f};

    for (int ks = 0; ks < KSTEPS; ks++){
        int k0 = ks*32 + lg*8;
        float4 va = {0.f,0.f,0.f,0.f}, vb = {0.f,0.f,0.f,0.f};
        if (k0 + 3 < K_REAL) va = *(const float4*)&arow[k0];
        if (k0 + 7 < K_REAL) vb = *(const float4*)&arow[k0 + 4];
        float f[8] = {va.x, va.y, va.z, va.w, vb.x, vb.y, vb.z, vb.w};
        bf16x8 ah, al;
        #pragma unroll
        for (int q = 0; q < 8; q++){
            bf16_t hi = (bf16_t)f[q];
            ah[q] = hi;
            al[q] = (bf16_t)(f[q] - (float)hi);
        }
        int g = ks*4 + lg;
        const bf16_t* bh_base = bHi + ((size_t)g*NCOL + l15)*8;
        const bf16_t* bl_base = bLo + ((size_t)g*NCOL + l15)*8;
        #pragma unroll
        for (int c = 0; c < NT; c++){
            bf16x8 bh = *(const bf16x8*)&bh_base[c*128];
            bf16x8 bl = *(const bf16x8*)&bl_base[c*128];
            acc[c] = __builtin_amdgcn_mfma_f32_16x16x32_bf16(ah, bh, acc[c], 0,0,0);
            acc[c] = __builtin_amdgcn_mfma_f32_16x16x32_bf16(ah, bl, acc[c], 0,0,0);
            acc[c] = __builtin_amdgcn_mfma_f32_16x16x32_bf16(al, bh, acc[c], 0,0,0);
        }
    }

    #pragma unroll
    for (int c = 0; c < 8; c++){
        int col = c*16 + l15;
        float bv = BIAS_EPI ? bias[col] : 0.f;
        #pragma unroll
        for (int r = 0; r < 4; r++){
            int m = m0 + lg*4 + r;
            if (!ALPHA) outF[(size_t)m*128 + col] = acc[c][r] + bv;
            else        outH[(size_t)m*128 + col] = (bf16_t)acc[c][r];
        }
    }
    if (ALPHA){
        #pragma unroll
        for (int r = 0; r < 4; r++){
            int m = m0 + lg*4 + r;
            float v = acc[8][r];
            if (l15 < 8) asrc_out[m*8 + l15]       = v;
            else         adst_out[m*8 + (l15 - 8)] = v;
        }
    }
}

// ---- Wa[k][j] = sum_d W[k][j*16+d]*a[j][d]  (j<8: src, j>=8: dst) ----
__global__ void wa_kernel(const float* __restrict__ W, const float* __restrict__ as,
                          const float* __restrict__ ad, float* __restrict__ Wa){
    int k = threadIdx.x;   // 128
    #pragma unroll
    for (int j = 0; j < 8; j++){
        float s1 = 0.f, s2 = 0.f;
        #pragma unroll
        for (int d = 0; d < 16; d++){
            float wv = W[k*128 + j*16 + d];
            s1 += wv * as[j*16 + d];
            s2 += wv * ad[j*16 + d];
        }
        Wa[k*16 + j]     = s1;
        Wa[k*16 + 8 + j] = s2;
    }
}

// ============== CSR build, XCD-partitioned by dst range ==============
__global__ __launch_bounds__(256)
void deg_part_kernel(const int* __restrict__ ei, int* __restrict__ deg){
    int part = blockIdx.x & 7;
    int bwp  = blockIdx.x >> 3;
    int nbp  = gridDim.x >> 3;
    int lo = part*PSZ, hi = lo + PSZ;
    for (int e = bwp*256 + threadIdx.x; e < E_TOT; e += nbp*256){
        int d = (e < N_EDGESI) ? ei[N_EDGESI + e] : (e - N_EDGESI);
        if (d >= lo && d < hi) atomicAdd(&deg[d], 1);
    }
}

__global__ __launch_bounds__(256)
void scatter_part_kernel(const int* __restrict__ ei, int* __restrict__ cursor,
                         int* __restrict__ col_src){
    int part = blockIdx.x & 7;
    int bwp  = blockIdx.x >> 3;
    int nbp  = gridDim.x >> 3;
    int lo = part*PSZ, hi = lo + PSZ;
    for (int e = bwp*256 + threadIdx.x; e < E_TOT; e += nbp*256){
        int d = (e < N_EDGESI) ? ei[N_EDGESI + e] : (e - N_EDGESI);
        if (d >= lo && d < hi){
            int s = (e < N_EDGESI) ? ei[e] : d;
            int pos = atomicAdd(&cursor[d], 1);
            col_src[pos] = s;
        }
    }
}

__global__ void scan_block_kernel(const int* __restrict__ deg, int* __restrict__ scanout,
                                  int* __restrict__ blocksums){
    __shared__ int buf[1024];
    int gid = blockIdx.x*1024 + threadIdx.x;
    int v = (gid < N_NODES) ? deg[gid] : 0;
    buf[threadIdx.x] = v;
    __syncthreads();
    for (int off = 1; off < 1024; off <<= 1){
        int t = (threadIdx.x >= off) ? buf[threadIdx.x - off] : 0;
        __syncthreads();
        buf[threadIdx.x] += t;
        __syncthreads();
    }
    if (gid < N_NODES) scanout[gid] = buf[threadIdx.x] - v;   // exclusive
    if (threadIdx.x == 1023) blocksums[blockIdx.x] = buf[1023];
}

// wave-parallel exclusive scan of <=64 block sums
__global__ void scan_sums_kernel(int* __restrict__ blocksums, int nb){
    int t = threadIdx.x;   // 64
    int orig = (t < nb) ? blocksums[t] : 0;
    int v = orig;
    #pragma unroll
    for (int off = 1; off < 64; off <<= 1){
        int u = __shfl_up(v, off);
        if (t >= off) v += u;
    }
    if (t < nb) blocksums[t] = v - orig;   // exclusive
}

__global__ void scan_add_kernel(const int* __restrict__ scanout, const int* __restrict__ blocksums,
                                int* __restrict__ row_ptr, int* __restrict__ cursor){
    int i = blockIdx.x*256 + threadIdx.x;
    if (i < N_NODES){
        int v = scanout[i] + blocksums[i >> 10];
        row_ptr[i] = v;
        cursor[i]  = v;
    }
    if (i == 0) row_ptr[N_NODES] = E_TOT;
}

// ===== fused per-dst softmax + aggregate + bias + ELU: one wave per node =====
__global__ __launch_bounds__(256)
void gat_aggregate_kernel(const int* __restrict__ row_ptr, const int* __restrict__ col_src,
                          const unsigned short* __restrict__ H, const float* __restrict__ a_s,
                          const float* __restrict__ a_d, const float* __restrict__ bias,
                          float* __restrict__ xout){
    __shared__ float alds[4][8][65];
    int wave = threadIdx.x >> 6;
    int lane = threadIdx.x & 63;
    int d = blockIdx.x*4 + wave;
    if (d >= N_NODES) return;
    int start = row_ptr[d], end = row_ptr[d + 1];
    int deg = end - start;                 // >= 1 (self loop)
    int hme = lane >> 3, seg = lane & 7;

    float ad_[8];
    {
        float4 t0 = *(const float4*)&a_d[d*8];
        float4 t1 = *(const float4*)&a_d[d*8 + 4];
        ad_[0]=t0.x; ad_[1]=t0.y; ad_[2]=t0.z; ad_[3]=t0.w;
        ad_[4]=t1.x; ad_[5]=t1.y; ad_[6]=t1.z; ad_[7]=t1.w;
    }

    float acc0 = 0.f, acc1 = 0.f, dh;
    unsigned hoff = 2u*lane;

    if (deg <= 64){
        bool act = lane < deg;
        int sreg = 0;
        float e[8];
        #pragma unroll
        for (int h = 0; h < 8; h++) e[h] = 0.f;
        if (act){
            sreg = col_src[start + lane];
            float4 s0 = *(const float4*)&a_s[sreg*8];
            float4 s1 = *(const float4*)&a_s[sreg*8 + 4];
            float as_[8] = {s0.x,s0.y,s0.z,s0.w,s1.x,s1.y,s1.z,s1.w};
            #pragma unroll
            for (int h = 0; h < 8; h++){
                float v = as_[h] + ad_[h];
                v = v > 0.f ? v : 0.2f*v;
                e[h] = __expf(fminf(v, 70.f));
            }
        }
        #pragma unroll
        for (int h = 0; h < 8; h++) alds[wave][h][lane] = e[h];

        const float* row = &alds[wave][hme][0];
        float s = 0.f;
        #pragma unroll
        for (int j = 0; j < 8; j++) s += row[seg*8 + j];
        s += __shfl_xor(s, 1); s += __shfl_xor(s, 2); s += __shfl_xor(s, 4);
        dh = 1.0f / s;

        int p = 0;
        for (; p + 4 <= deg; p += 4){
            int s0 = __shfl(sreg, p+0), s1 = __shfl(sreg, p+1);
            int s2 = __shfl(sreg, p+2), s3 = __shfl(sreg, p+3);
            unsigned g0 = *(const unsigned*)&H[(size_t)s0*128 + hoff];
            unsigned g1 = *(const unsigned*)&H[(size_t)s1*128 + hoff];
            unsigned g2 = *(const unsigned*)&H[(size_t)s2*128 + hoff];
            unsigned g3 = *(const unsigned*)&H[(size_t)s3*128 + hoff];
            float a0 = row[p+0], a1 = row[p+1], a2 = row[p+2], a3 = row[p+3];
            acc0 += bflo(g0)*a0 + bflo(g1)*a1 + bflo(g2)*a2 + bflo(g3)*a3;
            acc1 += bfhi(g0)*a0 + bfhi(g1)*a1 + bfhi(g2)*a2 + bfhi(g3)*a3;
        }
        for (; p < deg; p++){
            int s0 = __shfl(sreg, p);
            unsigned g0 = *(const unsigned*)&H[(size_t)s0*128 + hoff];
            float a0 = row[p];
            acc0 += bflo(g0)*a0;
            acc1 += bfhi(g0)*a0;
        }
    } else {
        float adh = ad_[hme];
        float s = 0.f;
        for (int p = start + seg; p < end; p += 8){
            int sn = col_src[p];
            float v = a_s[sn*8 + hme] + adh;
            v = v > 0.f ? v : 0.2f*v;
            s += __expf(fminf(v, 70.f));
        }
        s += __shfl_xor(s, 1); s += __shfl_xor(s, 2); s += __shfl_xor(s, 4);
        dh = 1.0f / s;
        for (int p = start; p < end; p++){
            int sn = col_src[p];
            float v = a_s[sn*8 + hme] + adh;
            v = v > 0.f ? v : 0.2f*v;
            float a = __expf(fminf(v, 70.f));
            unsigned g = *(const unsigned*)&H[(size_t)sn*128 + hoff];
            acc0 += bflo(g)*a;
            acc1 += bfhi(g)*a;
        }
    }

    float o0 = acc0*dh + bias[2*lane];
    float o1 = acc1*dh + bias[2*lane + 1];
    o0 = o0 > 0.f ? o0 : expm1f(o0);
    o1 = o1 > 0.f ? o1 : expm1f(o1);
    float2 o = {o0, o1};
    *(float2*)&xout[(size_t)d*HIDDEN + 2*lane] = o;
}

// ---- scores + loss fused ----
__global__ void head_kernel(const float* __restrict__ x, const int* __restrict__ tgt,
                            const float* __restrict__ w, const float* __restrict__ b,
                            float* __restrict__ dout){
    int t = threadIdx.x;   // 64 = BATCH
    const float* row = x + (size_t)tgt[t]*HIDDEN;
    float v = 0.f;
    #pragma unroll
    for (int c = 0; c < HIDDEN; c += 4){
        float4 xv = *(const float4*)&row[c];
        float4 wv = *(const float4*)&w[c];
        v += xv.x*wv.x + xv.y*wv.y + xv.z*wv.z + xv.w*wv.w;
    }
    float sc = v + b[0];
    dout[t] = sc;
    float neg = __shfl(sc, t + 32);
    float dlt = 1.0f - (sc - neg);
    float term = (t < 32) ? (dlt > 0.f ? dlt : 0.f) : 0.f;
    #pragma unroll
    for (int m = 32; m >= 1; m >>= 1) term += __shfl_xor(term, m);
    if (t == 0) dout[BATCH] = term * (1.0f/32.0f);
}

extern "C" void kernel_launch(void* const* d_in, const int* in_sizes, int n_in,
                              void* d_out, int out_size, void* d_ws, size_t ws_size,
                              hipStream_t stream) {
    const float* word   = (const float*)d_in[0];
    const int*   ei     = (const int*)  d_in[1];
    const int*   tgt    = (const int*)  d_in[2];
    const float* lin1W  = (const float*)d_in[4];
    const float* lin1b  = (const float*)d_in[5];
    const float* gatW   = (const float*)d_in[6];
    const float* attS   = (const float*)d_in[7];
    const float* attD   = (const float*)d_in[8];
    const float* gatB   = (const float*)d_in[9];
    const float* lin3W  = (const float*)d_in[10];
    const float* lin3b  = (const float*)d_in[11];

    char* ws = (char*)d_ws;
    size_t off = 0;
    float*   x       = (float*)(ws + off);   off += (size_t)N_NODES*HIDDEN*4;
    bf16_t*  Hb      = (bf16_t*)(ws + off);  off += (size_t)N_NODES*HIDDEN*2;
    float*   a_s     = (float*)(ws + off);   off += (size_t)N_NODES*HEADS*4;
    float*   a_d     = (float*)(ws + off);   off += (size_t)N_NODES*HEADS*4;
    int*     deg     = (int*)(ws + off);     off += (size_t)(N_NODES + 16)*4;
    int*     scantmp = (int*)(ws + off);     off += (size_t)(N_NODES + 16)*4;
    int*     bsums   = (int*)(ws + off);     off += 1024;
    int*     row_ptr = (int*)(ws + off);     off += (size_t)(N_NODES + 16)*4;
    int*     cursor  = (int*)(ws + off);     off += (size_t)(N_NODES + 16)*4;
    int*     col_src = (int*)(ws + off);     off += (size_t)E_TOT*4;
    bf16_t*  b1Hi    = (bf16_t*)(ws + off);  off += (size_t)320*128*2;
    bf16_t*  b1Lo    = (bf16_t*)(ws + off);  off += (size_t)320*128*2;
    bf16_t*  b2Hi    = (bf16_t*)(ws + off);  off += (size_t)128*144*2;
    bf16_t*  b2Lo    = (bf16_t*)(ws + off);  off += (size_t)128*144*2;
    float*   Wa      = (float*)(ws + off);   off += 128*16*4;

    const int NB = (N_NODES + 255)/256;
    const int SB = (N_NODES + 1023)/1024;
    const int GB = ((N_NODES + 15)/16 + 3)/4;
    const int PB = 8*128;                    // partitioned CSR kernels

    // ---- CSR build (once), XCD-partitioned ----
    hipMemsetAsync(deg, 0, (size_t)N_NODES*4, stream);
    deg_part_kernel  <<<PB, 256, 0, stream>>>(ei, deg);
    scan_block_kernel<<<SB, 1024, 0, stream>>>(deg, scantmp, bsums);
    scan_sums_kernel <<<1, 64, 0, stream>>>(bsums, SB);
    scan_add_kernel  <<<NB, 256, 0, stream>>>(scantmp, bsums, row_ptr, cursor);
    scatter_part_kernel<<<PB, 256, 0, stream>>>(ei, cursor, col_src);

    // ---- lin1: x = word @ lin1_W + b ----
    pack_b_kernel<INPUT, 320, 128><<<(320*128 + 255)/256, 256, 0, stream>>>(
        lin1W, nullptr, b1Hi, b1Lo);
    mfma_gemm2_kernel<INPUT, 8, true, false><<<GB, 256, 0, stream>>>(
        word, b1Hi, b1Lo, lin1b, x, nullptr, nullptr, nullptr, N_NODES);

    for (int L = 0; L < 2; L++){
        const float* W = gatW + (size_t)L*HIDDEN*HIDDEN;
        wa_kernel<<<1, 128, 0, stream>>>(W, attS + L*HEADS*HEAD_DIM,
                                         attD + L*HEADS*HEAD_DIM, Wa);
        pack_b_kernel<HIDDEN, 128, 144><<<(128*144 + 255)/256, 256, 0, stream>>>(
            W, Wa, b2Hi, b2Lo);
        mfma_gemm2_kernel<HIDDEN, 9, false, true><<<GB, 256, 0, stream>>>(
            x, b2Hi, b2Lo, nullptr, nullptr, Hb, a_s, a_d, N_NODES);
        gat_aggregate_kernel<<<(N_NODES + 3)/4, 256, 0, stream>>>(
            row_ptr, col_src, (const unsigned short*)Hb, a_s, a_d, gatB + L*HIDDEN, x);
    }

    head_kernel<<<1, 64, 0, stream>>>(x, tgt, lin3W, lin3b, (float*)d_out);
}

// Round 7
// 252.753 us; speedup vs baseline: 4.6704x; 1.0558x over previous
//
#include <hip/hip_runtime.h>
#include <math.h>

#define N_NODES 50000
#define N_EDGESI 800000
#define E_TOT   850000      // + self loops
#define HIDDEN  128
#define HEADS   8
#define HEAD_DIM 16
#define INPUT   300
#define BATCH   64
#define NPART   8
#define PSZ     6250        // N_NODES / NPART

typedef __bf16 bf16_t;
typedef bf16_t bf16x8 __attribute__((ext_vector_type(8)));
typedef float  f32x4  __attribute__((ext_vector_type(4)));

__device__ __forceinline__ float bflo(unsigned u){ return __uint_as_float(u << 16); }
__device__ __forceinline__ float bfhi(unsigned u){ return __uint_as_float(u & 0xffff0000u); }

// ===== pack B (fp32 -> fragment-ready bf16 hi/lo planes) + fused Wa =====
// layout: plane[(k/8)*NCOL*8 + col*8 + (k%8)]
// ALPHA: cols 128..143 are Wa[k][jj] = sum_d W[k][ (jj&7)*16+d ] * a[jj][d]
template<int K_REAL, int K_PAD, int NCOL, bool ALPHA>
__global__ void pack_b_kernel(const float* __restrict__ B128, const float* __restrict__ as,
                              const float* __restrict__ ad, bf16_t* __restrict__ bHi,
                              bf16_t* __restrict__ bLo){
    int idx = blockIdx.x*256 + threadIdx.x;
    if (idx >= K_PAD*NCOL) return;
    int k = idx / NCOL, col = idx % NCOL;
    float v = 0.f;
    if (k < K_REAL){
        if (!ALPHA || col < 128){
            v = B128[k*128 + col];
        } else {
            int jj = col - 128;                       // 0..15
            const float* a = (jj < 8) ? (as + jj*16) : (ad + (jj-8)*16);
            const float* wrow = B128 + k*128 + (jj & 7)*16;
            float s = 0.f;
            #pragma unroll
            for (int d = 0; d < 16; d++) s += wrow[d]*a[d];
            v = s;
        }
    }
    bf16_t hi = (bf16_t)v;
    bf16_t lo = (bf16_t)(v - (float)hi);
    int o = ((k >> 3)*NCOL + col)*8 + (k & 7);
    bHi[o] = hi; bLo[o] = lo;
}

// ===== MFMA GEMM, fp32 accuracy via bf16 hi/lo split, K-split 2x =====
// block = 256 thr = 2 row-tiles x 2 k-halves. wave (rt,kh): 16 rows, K/2.
// kh=1 writes partial acc to LDS; kh=0 combines + epilogue.
template<int K_REAL, int NT, bool BIAS_EPI, bool ALPHA>
__global__ __launch_bounds__(256)
void mfma_gemm3_kernel(const float* __restrict__ A, const bf16_t* __restrict__ bHi,
                       const bf16_t* __restrict__ bLo, const float* __restrict__ bias,
                       float* __restrict__ outF, bf16_t* __restrict__ outH,
                       float* __restrict__ asrc_out, float* __restrict__ adst_out, int M)
{
    constexpr int NCOL   = NT * 16;
    constexpr int KSTEPS = (K_REAL + 31) / 32;
    static_assert(KSTEPS % 2 == 0, "");
    constexpr int KH = KSTEPS / 2;
    __shared__ f32x4 accL[2][NT*64];

    int tid = threadIdx.x, lane = tid & 63, w = tid >> 6;
    int l15 = lane & 15, lg = lane >> 4;
    int rt = w >> 1;                 // row tile within block
    int kh = w & 1;                  // k half
    int m0 = (blockIdx.x*2 + rt) * 16;
    int mrow = m0 + l15; if (mrow >= M) mrow = M - 1;   // clamp (safe garbage)
    const float* arow = A + (size_t)mrow*K_REAL;

    f32x4 acc[NT];
    #pragma unroll
    for (int c = 0; c < NT; c++) acc[c] = (f32x4){0.f,0.f,0.f,0.f};

    int ks0 = kh * KH;
    float4 va = {0.f,0.f,0.f,0.f}, vb = {0.f,0.f,0.f,0.f};
    {
        int k0 = ks0*32 + lg*8;
        if (k0 + 3 < K_REAL) va = *(const float4*)&arow[k0];
        if (k0 + 7 < K_REAL) vb = *(const float4*)&arow[k0 + 4];
    }
    #pragma unroll
    for (int i = 0; i < KH; i++){
        float4 nva = {0.f,0.f,0.f,0.f}, nvb = {0.f,0.f,0.f,0.f};
        if (i + 1 < KH){
            int k0 = (ks0 + i + 1)*32 + lg*8;
            if (k0 + 3 < K_REAL) nva = *(const float4*)&arow[k0];
            if (k0 + 7 < K_REAL) nvb = *(const float4*)&arow[k0 + 4];
        }
        float f[8] = {va.x, va.y, va.z, va.w, vb.x, vb.y, vb.z, vb.w};
        bf16x8 ah, al;
        #pragma unroll
        for (int q = 0; q < 8; q++){
            bf16_t hi = (bf16_t)f[q];
            ah[q] = hi;
            al[q] = (bf16_t)(f[q] - (float)hi);
        }
        int g = (ks0 + i)*4 + lg;
        const bf16_t* bh_base = bHi + ((size_t)g*NCOL + l15)*8;
        const bf16_t* bl_base = bLo + ((size_t)g*NCOL + l15)*8;
        #pragma unroll
        for (int c = 0; c < NT; c++){
            bf16x8 bh = *(const bf16x8*)&bh_base[c*128];
            bf16x8 bl = *(const bf16x8*)&bl_base[c*128];
            acc[c] = __builtin_amdgcn_mfma_f32_16x16x32_bf16(ah, bh, acc[c], 0,0,0);
            acc[c] = __builtin_amdgcn_mfma_f32_16x16x32_bf16(ah, bl, acc[c], 0,0,0);
            acc[c] = __builtin_amdgcn_mfma_f32_16x16x32_bf16(al, bh, acc[c], 0,0,0);
        }
        va = nva; vb = nvb;
    }

    // ---- combine k-halves through LDS ----
    if (kh == 1){
        #pragma unroll
        for (int c = 0; c < NT; c++) accL[rt][c*64 + lane] = acc[c];
    }
    __syncthreads();
    if (kh == 1) return;
    #pragma unroll
    for (int c = 0; c < NT; c++) acc[c] += accL[rt][c*64 + lane];

    // ---- epilogue: D col = lane&15, row = (lane>>4)*4 + reg ----
    #pragma unroll
    for (int c = 0; c < 8; c++){
        int col = c*16 + l15;
        float bv = BIAS_EPI ? bias[col] : 0.f;
        #pragma unroll
        for (int r = 0; r < 4; r++){
            int m = m0 + lg*4 + r;
            if (m < M){
                if (!ALPHA) outF[(size_t)m*128 + col] = acc[c][r] + bv;
                else        outH[(size_t)m*128 + col] = (bf16_t)acc[c][r];
            }
        }
    }
    if (ALPHA){
        #pragma unroll
        for (int r = 0; r < 4; r++){
            int m = m0 + lg*4 + r;
            if (m < M){
                float v = acc[8][r];
                if (l15 < 8) asrc_out[m*8 + l15]       = v;
                else         adst_out[m*8 + (l15 - 8)] = v;
            }
        }
    }
}

// ============== CSR build, XCD-partitioned by dst range ==============
__global__ __launch_bounds__(256)
void deg_part_kernel(const int* __restrict__ ei, int* __restrict__ deg){
    int part = blockIdx.x & 7;
    int bwp  = blockIdx.x >> 3;
    int nbp  = gridDim.x >> 3;
    int lo = part*PSZ, hi = lo + PSZ;
    for (int e = bwp*256 + threadIdx.x; e < E_TOT; e += nbp*256){
        int d = (e < N_EDGESI) ? ei[N_EDGESI + e] : (e - N_EDGESI);
        if (d >= lo && d < hi) atomicAdd(&deg[d], 1);
    }
}

__global__ __launch_bounds__(256)
void scatter_part_kernel(const int* __restrict__ ei, int* __restrict__ cursor,
                         int* __restrict__ col_src){
    int part = blockIdx.x & 7;
    int bwp  = blockIdx.x >> 3;
    int nbp  = gridDim.x >> 3;
    int lo = part*PSZ, hi = lo + PSZ;
    for (int e = bwp*256 + threadIdx.x; e < E_TOT; e += nbp*256){
        int d = (e < N_EDGESI) ? ei[N_EDGESI + e] : (e - N_EDGESI);
        if (d >= lo && d < hi){
            int s = (e < N_EDGESI) ? ei[e] : d;
            int pos = atomicAdd(&cursor[d], 1);
            col_src[pos] = s;
        }
    }
}

__global__ void scan_block_kernel(const int* __restrict__ deg, int* __restrict__ scanout,
                                  int* __restrict__ blocksums){
    __shared__ int buf[1024];
    int gid = blockIdx.x*1024 + threadIdx.x;
    int v = (gid < N_NODES) ? deg[gid] : 0;
    buf[threadIdx.x] = v;
    __syncthreads();
    for (int off = 1; off < 1024; off <<= 1){
        int t = (threadIdx.x >= off) ? buf[threadIdx.x - off] : 0;
        __syncthreads();
        buf[threadIdx.x] += t;
        __syncthreads();
    }
    if (gid < N_NODES) scanout[gid] = buf[threadIdx.x] - v;   // exclusive
    if (threadIdx.x == 1023) blocksums[blockIdx.x] = buf[1023];
}

// wave-parallel exclusive scan of <=64 block sums
__global__ void scan_sums_kernel(int* __restrict__ blocksums, int nb){
    int t = threadIdx.x;   // 64
    int orig = (t < nb) ? blocksums[t] : 0;
    int v = orig;
    #pragma unroll
    for (int off = 1; off < 64; off <<= 1){
        int u = __shfl_up(v, off);
        if (t >= off) v += u;
    }
    if (t < nb) blocksums[t] = v - orig;   // exclusive
}

__global__ void scan_add_kernel(const int* __restrict__ scanout, const int* __restrict__ blocksums,
                                int* __restrict__ row_ptr, int* __restrict__ cursor){
    int i = blockIdx.x*256 + threadIdx.x;
    if (i < N_NODES){
        int v = scanout[i] + blocksums[i >> 10];
        row_ptr[i] = v;
        cursor[i]  = v;
    }
    if (i == 0) row_ptr[N_NODES] = E_TOT;
}

// ===== fused per-dst softmax + aggregate + bias + ELU: one wave per node =====
__global__ __launch_bounds__(256)
void gat_aggregate_kernel(const int* __restrict__ row_ptr, const int* __restrict__ col_src,
                          const unsigned short* __restrict__ H, const float* __restrict__ a_s,
                          const float* __restrict__ a_d, const float* __restrict__ bias,
                          float* __restrict__ xout){
    __shared__ float alds[4][8][65];
    int wave = threadIdx.x >> 6;
    int lane = threadIdx.x & 63;
    int d = blockIdx.x*4 + wave;
    if (d >= N_NODES) return;
    int start = row_ptr[d], end = row_ptr[d + 1];
    int deg = end - start;                 // >= 1 (self loop)
    int hme = lane >> 3, seg = lane & 7;

    float ad_[8];
    {
        float4 t0 = *(const float4*)&a_d[d*8];
        float4 t1 = *(const float4*)&a_d[d*8 + 4];
        ad_[0]=t0.x; ad_[1]=t0.y; ad_[2]=t0.z; ad_[3]=t0.w;
        ad_[4]=t1.x; ad_[5]=t1.y; ad_[6]=t1.z; ad_[7]=t1.w;
    }

    float acc0 = 0.f, acc1 = 0.f, dh;
    unsigned hoff = 2u*lane;

    if (deg <= 64){
        bool act = lane < deg;
        int sreg = 0;
        float e[8];
        #pragma unroll
        for (int h = 0; h < 8; h++) e[h] = 0.f;
        if (act){
            sreg = col_src[start + lane];
            float4 s0 = *(const float4*)&a_s[sreg*8];
            float4 s1 = *(const float4*)&a_s[sreg*8 + 4];
            float as_[8] = {s0.x,s0.y,s0.z,s0.w,s1.x,s1.y,s1.z,s1.w};
            #pragma unroll
            for (int h = 0; h < 8; h++){
                float v = as_[h] + ad_[h];
                v = v > 0.f ? v : 0.2f*v;
                e[h] = __expf(fminf(v, 70.f));
            }
        }
        #pragma unroll
        for (int h = 0; h < 8; h++) alds[wave][h][lane] = e[h];

        const float* row = &alds[wave][hme][0];
        float s = 0.f;
        #pragma unroll
        for (int j = 0; j < 8; j++) s += row[seg*8 + j];
        s += __shfl_xor(s, 1); s += __shfl_xor(s, 2); s += __shfl_xor(s, 4);
        dh = 1.0f / s;

        int p = 0;
        for (; p + 4 <= deg; p += 4){
            int s0 = __shfl(sreg, p+0), s1 = __shfl(sreg, p+1);
            int s2 = __shfl(sreg, p+2), s3 = __shfl(sreg, p+3);
            unsigned g0 = *(const unsigned*)&H[(size_t)s0*128 + hoff];
            unsigned g1 = *(const unsigned*)&H[(size_t)s1*128 + hoff];
            unsigned g2 = *(const unsigned*)&H[(size_t)s2*128 + hoff];
            unsigned g3 = *(const unsigned*)&H[(size_t)s3*128 + hoff];
            float a0 = row[p+0], a1 = row[p+1], a2 = row[p+2], a3 = row[p+3];
            acc0 += bflo(g0)*a0 + bflo(g1)*a1 + bflo(g2)*a2 + bflo(g3)*a3;
            acc1 += bfhi(g0)*a0 + bfhi(g1)*a1 + bfhi(g2)*a2 + bfhi(g3)*a3;
        }
        for (; p < deg; p++){
            int s0 = __shfl(sreg, p);
            unsigned g0 = *(const unsigned*)&H[(size_t)s0*128 + hoff];
            float a0 = row[p];
            acc0 += bflo(g0)*a0;
            acc1 += bfhi(g0)*a0;
        }
    } else {
        float adh = ad_[hme];
        float s = 0.f;
        for (int p = start + seg; p < end; p += 8){
            int sn = col_src[p];
            float v = a_s[sn*8 + hme] + adh;
            v = v > 0.f ? v : 0.2f*v;
            s += __expf(fminf(v, 70.f));
        }
        s += __shfl_xor(s, 1); s += __shfl_xor(s, 2); s += __shfl_xor(s, 4);
        dh = 1.0f / s;
        for (int p = start; p < end; p++){
            int sn = col_src[p];
            float v = a_s[sn*8 + hme] + adh;
            v = v > 0.f ? v : 0.2f*v;
            float a = __expf(fminf(v, 70.f));
            unsigned g = *(const unsigned*)&H[(size_t)sn*128 + hoff];
            acc0 += bflo(g)*a;
            acc1 += bfhi(g)*a;
        }
    }

    float o0 = acc0*dh + bias[2*lane];
    float o1 = acc1*dh + bias[2*lane + 1];
    o0 = o0 > 0.f ? o0 : expm1f(o0);
    o1 = o1 > 0.f ? o1 : expm1f(o1);
    float2 o = {o0, o1};
    *(float2*)&xout[(size_t)d*HIDDEN + 2*lane] = o;
}

// ---- scores + loss fused ----
__global__ void head_kernel(const float* __restrict__ x, const int* __restrict__ tgt,
                            const float* __restrict__ w, const float* __restrict__ b,
                            float* __restrict__ dout){
    int t = threadIdx.x;   // 64 = BATCH
    const float* row = x + (size_t)tgt[t]*HIDDEN;
    float v = 0.f;
    #pragma unroll
    for (int c = 0; c < HIDDEN; c += 4){
        float4 xv = *(const float4*)&row[c];
        float4 wv = *(const float4*)&w[c];
        v += xv.x*wv.x + xv.y*wv.y + xv.z*wv.z + xv.w*wv.w;
    }
    float sc = v + b[0];
    dout[t] = sc;
    float neg = __shfl(sc, t + 32);
    float dlt = 1.0f - (sc - neg);
    float term = (t < 32) ? (dlt > 0.f ? dlt : 0.f) : 0.f;
    #pragma unroll
    for (int m = 32; m >= 1; m >>= 1) term += __shfl_xor(term, m);
    if (t == 0) dout[BATCH] = term * (1.0f/32.0f);
}

extern "C" void kernel_launch(void* const* d_in, const int* in_sizes, int n_in,
                              void* d_out, int out_size, void* d_ws, size_t ws_size,
                              hipStream_t stream) {
    const float* word   = (const float*)d_in[0];
    const int*   ei     = (const int*)  d_in[1];
    const int*   tgt    = (const int*)  d_in[2];
    const float* lin1W  = (const float*)d_in[4];
    const float* lin1b  = (const float*)d_in[5];
    const float* gatW   = (const float*)d_in[6];
    const float* attS   = (const float*)d_in[7];
    const float* attD   = (const float*)d_in[8];
    const float* gatB   = (const float*)d_in[9];
    const float* lin3W  = (const float*)d_in[10];
    const float* lin3b  = (const float*)d_in[11];

    char* ws = (char*)d_ws;
    size_t off = 0;
    float*   x       = (float*)(ws + off);   off += (size_t)N_NODES*HIDDEN*4;
    bf16_t*  Hb      = (bf16_t*)(ws + off);  off += (size_t)N_NODES*HIDDEN*2;
    float*   a_s     = (float*)(ws + off);   off += (size_t)N_NODES*HEADS*4;
    float*   a_d     = (float*)(ws + off);   off += (size_t)N_NODES*HEADS*4;
    int*     deg     = (int*)(ws + off);     off += (size_t)(N_NODES + 16)*4;
    int*     scantmp = (int*)(ws + off);     off += (size_t)(N_NODES + 16)*4;
    int*     bsums   = (int*)(ws + off);     off += 1024;
    int*     row_ptr = (int*)(ws + off);     off += (size_t)(N_NODES + 16)*4;
    int*     cursor  = (int*)(ws + off);     off += (size_t)(N_NODES + 16)*4;
    int*     col_src = (int*)(ws + off);     off += (size_t)E_TOT*4;
    bf16_t*  b1Hi    = (bf16_t*)(ws + off);  off += (size_t)320*128*2;
    bf16_t*  b1Lo    = (bf16_t*)(ws + off);  off += (size_t)320*128*2;
    bf16_t*  b2Hi    = (bf16_t*)(ws + off);  off += (size_t)128*144*2;
    bf16_t*  b2Lo    = (bf16_t*)(ws + off);  off += (size_t)128*144*2;

    const int NB = (N_NODES + 255)/256;
    const int SB = (N_NODES + 1023)/1024;
    const int GB = (N_NODES + 31)/32;        // k-split gemm blocks (32 rows each)
    const int PB = 8*128;                    // partitioned CSR kernels

    // ---- CSR build (once), XCD-partitioned ----
    hipMemsetAsync(deg, 0, (size_t)N_NODES*4, stream);
    deg_part_kernel  <<<PB, 256, 0, stream>>>(ei, deg);
    scan_block_kernel<<<SB, 1024, 0, stream>>>(deg, scantmp, bsums);
    scan_sums_kernel <<<1, 64, 0, stream>>>(bsums, SB);
    scan_add_kernel  <<<NB, 256, 0, stream>>>(scantmp, bsums, row_ptr, cursor);
    scatter_part_kernel<<<PB, 256, 0, stream>>>(ei, cursor, col_src);

    // ---- lin1: x = word @ lin1_W + b ----
    pack_b_kernel<INPUT, 320, 128, false><<<(320*128 + 255)/256, 256, 0, stream>>>(
        lin1W, nullptr, nullptr, b1Hi, b1Lo);
    mfma_gemm3_kernel<INPUT, 8, true, false><<<GB, 256, 0, stream>>>(
        word, b1Hi, b1Lo, lin1b, x, nullptr, nullptr, nullptr, N_NODES);

    for (int L = 0; L < 2; L++){
        const float* W = gatW + (size_t)L*HIDDEN*HIDDEN;
        pack_b_kernel<HIDDEN, 128, 144, true><<<(128*144 + 255)/256, 256, 0, stream>>>(
            W, attS + L*HEADS*HEAD_DIM, attD + L*HEADS*HEAD_DIM, b2Hi, b2Lo);
        mfma_gemm3_kernel<HIDDEN, 9, false, true><<<GB, 256, 0, stream>>>(
            x, b2Hi, b2Lo, nullptr, nullptr, Hb, a_s, a_d, N_NODES);
        gat_aggregate_kernel<<<(N_NODES + 3)/4, 256, 0, stream>>>(
            row_ptr, col_src, (const unsigned short*)Hb, a_s, a_d, gatB + L*HIDDEN, x);
    }

    head_kernel<<<1, 64, 0, stream>>>(x, tgt, lin3W, lin3b, (float*)d_out);
}